// Round 15
// baseline (250.142 us; speedup 1.0000x reference)
//
#include <hip/hip_runtime.h>
#include <stdint.h>

#define B_ 2
#define S_ 2048
#define D_ 1024
#define H_ 16
#define HD_ 64
#define DFF_ 4096
#define M_ 4096        // B*S
#define QKV_STR 3072   // fused QKV row stride

typedef float           f4_t  __attribute__((ext_vector_type(4)));
typedef unsigned int    ui4_t __attribute__((ext_vector_type(4)));
typedef unsigned int    ui2_t __attribute__((ext_vector_type(2)));
typedef unsigned short  us4_t __attribute__((ext_vector_type(4)));
typedef unsigned short  us8_t __attribute__((ext_vector_type(8)));
typedef __bf16          bf8_t __attribute__((ext_vector_type(8)));

__device__ __forceinline__ float b2f(unsigned short u) {
    union { unsigned int u; float f; } v; v.u = ((unsigned int)u) << 16; return v.f;
}
__device__ __forceinline__ unsigned short f2b(float f) {
    union { float f; unsigned int u; } v; v.f = f;
    unsigned int u = v.u + 0x7fffu + ((v.u >> 16) & 1u);
    return (unsigned short)(u >> 16);
}
__device__ __forceinline__ unsigned cvt_pk_bf16(float lo, float hi) {
    unsigned r;
    asm("v_cvt_pk_bf16_f32 %0, %1, %2" : "=v"(r) : "v"(lo), "v"(hi));
    return r;
}
__device__ __forceinline__ void gll16(const unsigned short* g, unsigned short* l) {
    __builtin_amdgcn_global_load_lds((const __attribute__((address_space(1))) unsigned int*)g,
                                     (__attribute__((address_space(3))) unsigned int*)l,
                                     16, 0, 0);
}

// ---------------- fused prep: 6 weight transposes + bias concat + rope table ----------------
__global__ __launch_bounds__(256) void k_prep(const float* __restrict__ Wq, const float* __restrict__ Wk,
                                              const float* __restrict__ Wv, const float* __restrict__ Wo,
                                              const float* __restrict__ W1, const float* __restrict__ W2,
                                              const float* __restrict__ bq, const float* __restrict__ bk,
                                              const float* __restrict__ bv,
                                              unsigned short* __restrict__ WqkvT, unsigned short* __restrict__ WoT,
                                              unsigned short* __restrict__ W1T, unsigned short* __restrict__ W2T,
                                              float* __restrict__ bqkv, float* __restrict__ tab) {
    const int j = blockIdx.x;
    if (j < 12288) {
        const float* src; unsigned short* dst; int R, C, jj;
        if (j < 3072)      { const int r = j >> 10; src = r == 0 ? Wq : (r == 1 ? Wk : Wv);
                             dst = WqkvT + (size_t)r * 1024 * 1024; R = 1024; C = 1024; jj = j & 1023; }
        else if (j < 4096) { src = Wo; dst = WoT; R = 1024; C = 1024; jj = j - 3072; }
        else if (j < 8192) { src = W1; dst = W1T; R = 1024; C = 4096; jj = j - 4096; }
        else               { src = W2; dst = W2T; R = 4096; C = 1024; jj = j - 8192; }
        const int ntx = C >> 5;
        const int bc = (jj % ntx) * 32, br = (jj / ntx) * 32;
        __shared__ float tile[32][33];
        const int tx = threadIdx.x & 31, ty = threadIdx.x >> 5;
#pragma unroll
        for (int i = ty; i < 32; i += 8)
            tile[i][tx] = src[(size_t)(br + i) * C + bc + tx];
        __syncthreads();
#pragma unroll
        for (int i = ty; i < 32; i += 8)
            dst[(size_t)(bc + i) * R + br + tx] = f2b(tile[tx][i]);
    } else if (j < 12300) {
        const int t = (j - 12288) * 256 + threadIdx.x;
        if (t < 1024) bqkv[t] = bq[t];
        else if (t < 2048) bqkv[t] = bk[t - 1024];
        else if (t < 3072) bqkv[t] = bv[t - 2048];
    } else {
        const int base = (j - 12300) * 256 + threadIdx.x;
#pragma unroll
        for (int e = 0; e < 32; e++) {
            const int idx = base + e * 2048;
            const int s = idx >> 5, i = idx & 31;
            const float freq = exp2f(-(float)i * 0.4152410118609203f);
            float sn, cs;
            sincosf((float)s * freq, &sn, &cs);
            tab[s * 64 + i] = cs;
            tab[s * 64 + 32 + i] = sn;
        }
    }
}

// ---------------- layernorm fp32 row(1024) -> bf16 ----------------
__global__ __launch_bounds__(256) void k_layernorm(const float* __restrict__ x,
                                                   const float* __restrict__ g,
                                                   const float* __restrict__ be,
                                                   unsigned short* __restrict__ out) {
    const int row = blockIdx.x;
    const int t = threadIdx.x;
    const float* xr = x + (size_t)row * D_;
    f4_t v = *(const f4_t*)&xr[t * 4];
    float s = v[0] + v[1] + v[2] + v[3];
#pragma unroll
    for (int o = 32; o >= 1; o >>= 1) s += __shfl_down(s, o);
    __shared__ float red[4];
    const int w = t >> 6, lane = t & 63;
    if (lane == 0) red[w] = s;
    __syncthreads();
    const float mean = (red[0] + red[1] + red[2] + red[3]) * (1.f / D_);
    f4_t d;
#pragma unroll
    for (int c = 0; c < 4; c++) d[c] = v[c] - mean;
    float ss = d[0]*d[0] + d[1]*d[1] + d[2]*d[2] + d[3]*d[3];
#pragma unroll
    for (int o = 32; o >= 1; o >>= 1) ss += __shfl_down(ss, o);
    __syncthreads();
    if (lane == 0) red[w] = ss;
    __syncthreads();
    const float var = (red[0] + red[1] + red[2] + red[3]) * (1.f / D_);
    const float rstd = rsqrtf(var + 1e-5f);
    f4_t gv = *(const f4_t*)&g[t * 4];
    f4_t bv = *(const f4_t*)&be[t * 4];
    us4_t o4;
#pragma unroll
    for (int c = 0; c < 4; c++) o4[c] = f2b(d[c] * rstd * gv[c] + bv[c]);
    *(us4_t*)&out[(size_t)row * D_ + t * 4] = o4;
}

#define VMW(n) asm volatile("s_waitcnt vmcnt(" #n ")" ::: "memory")
#define BAR()  __builtin_amdgcn_s_barrier()

// ---------------- bf16 MFMA GEMM 128x128, BK=32, counted-vmcnt dbuf, XCD-chunked 1D grid ----------------
// ROPE: fused rotary on Q/K column blocks using cos/sin table, bias added first.
// SPLIT: K-split partial (half = nid>>8), bf16 raw store.
template<int RELU, int BF16OUT, int RESID, int ROPE, int SPLIT>
__global__ __launch_bounds__(256) void k_gemm_bt(const unsigned short* __restrict__ A,
                                                 const unsigned short* __restrict__ Bt,
                                                 const float* __restrict__ bias,
                                                 const float* __restrict__ resid,
                                                 void* __restrict__ Cout,
                                                 const float* __restrict__ tab,
                                                 int M, int N, int K, int ldk, int nbx) {
    __shared__ __align__(16) unsigned short As0[128 * 32];
    __shared__ __align__(16) unsigned short Bs0[128 * 32];
    __shared__ __align__(16) unsigned short As1[128 * 32];
    __shared__ __align__(16) unsigned short Bs1[128 * 32];
    const int tid = threadIdx.x;
    const int cpx = gridDim.x >> 3;
    int nid = (blockIdx.x & 7) * cpx + (blockIdx.x >> 3);
    int half = 0;
    if (SPLIT) { half = nid >> 8; nid &= 255; A += 2048 * half; Bt += 2048 * half; }
    const int m0 = (nid / nbx) * 128, n0 = (nid % nbx) * 128;
    const int w = tid >> 6, lane = tid & 63;
    const int wr = w >> 1, wc = w & 1;
    const int lr = lane & 15, lg = lane >> 4;

    f4_t acc[4][4] = {};

    const int r1 = tid >> 2, q1 = tid & 3;
    const unsigned short* pA1 = A + (size_t)(m0 + r1) * ldk + q1 * 8;
    const unsigned short* pA2 = pA1 + (size_t)64 * ldk;
    const unsigned short* pB1 = Bt + (size_t)(n0 + r1) * ldk + q1 * 8;
    const unsigned short* pB2 = pB1 + (size_t)64 * ldk;
    const int wofs = w * 512;

#define STAGE(AS, BS, kk) do {                 \
        gll16(pA1 + (kk), (AS) + wofs);        \
        gll16(pA2 + (kk), (AS) + 2048 + wofs); \
        gll16(pB1 + (kk), (BS) + wofs);        \
        gll16(pB2 + (kk), (BS) + 2048 + wofs); } while (0)

#define COMPUTE(AS, BS) do {                                                     \
        bf8_t af[4], bfr[4];                                                     \
        _Pragma("unroll")                                                        \
        for (int f = 0; f < 4; f++) {                                            \
            af[f]  = *(const bf8_t*)&(AS)[(wr * 64 + f * 16 + lr) * 32 + lg * 8];\
            bfr[f] = *(const bf8_t*)&(BS)[(wc * 64 + f * 16 + lr) * 32 + lg * 8];\
        }                                                                        \
        _Pragma("unroll")                                                        \
        for (int mf = 0; mf < 4; mf++)                                           \
            _Pragma("unroll")                                                    \
            for (int nf = 0; nf < 4; nf++)                                       \
                acc[mf][nf] = __builtin_amdgcn_mfma_f32_16x16x32_bf16(           \
                    af[mf], bfr[nf], acc[mf][nf], 0, 0, 0); } while (0)

    STAGE(As0, Bs0, 0);
    for (int k0 = 0; k0 + 64 < K; k0 += 64) {
        STAGE(As1, Bs1, k0 + 32);
        VMW(4); BAR();
        COMPUTE(As0, Bs0);
        BAR();
        STAGE(As0, Bs0, k0 + 64);
        VMW(4); BAR();
        COMPUTE(As1, Bs1);
        BAR();
    }
    STAGE(As1, Bs1, K - 32);
    VMW(4); BAR();
    COMPUTE(As0, Bs0);
    VMW(0); BAR();
    COMPUTE(As1, Bs1);
#undef STAGE
#undef COMPUTE

    if (SPLIT) {
        unsigned short* outp = (unsigned short*)Cout + (size_t)half * ((size_t)M * N);
#pragma unroll
        for (int mf = 0; mf < 4; mf++)
#pragma unroll
            for (int nf = 0; nf < 4; nf++) {
                const int n = n0 + wc * 64 + nf * 16 + lr;
#pragma unroll
                for (int j = 0; j < 4; j++) {
                    const int m = m0 + wr * 64 + mf * 16 + lg * 4 + j;
                    outp[(size_t)m * N + n] = f2b(acc[mf][nf][j]);
                }
            }
        return;
    }
    if (ROPE) {
        // bias first (reference ropes post-bias)
#pragma unroll
        for (int mf = 0; mf < 4; mf++)
#pragma unroll
            for (int nf = 0; nf < 4; nf++) {
                const float bv = bias[n0 + wc * 64 + nf * 16 + lr];
#pragma unroll
                for (int j = 0; j < 4; j++) acc[mf][nf][j] += bv;
            }
        if (n0 < 2048) {   // Q or K block: rotate (i, i+32) pairs = (nf, nf+2), i = nf*16+lr
#pragma unroll
            for (int mf = 0; mf < 4; mf++)
#pragma unroll
                for (int j = 0; j < 4; j++) {
                    const int srow = (m0 + wr * 64 + mf * 16 + lg * 4 + j) & 2047;
                    const float* tr = tab + srow * 64;
#pragma unroll
                    for (int t = 0; t < 2; t++) {
                        const float cs = tr[t * 16 + lr];
                        const float sn = tr[32 + t * 16 + lr];
                        const float lo = acc[mf][t][j], hi = acc[mf][t + 2][j];
                        acc[mf][t][j]     = lo * cs - hi * sn;
                        acc[mf][t + 2][j] = hi * cs + lo * sn;
                    }
                }
        }
        unsigned short* outp = (unsigned short*)Cout;
#pragma unroll
        for (int mf = 0; mf < 4; mf++)
#pragma unroll
            for (int nf = 0; nf < 4; nf++) {
                const int n = n0 + wc * 64 + nf * 16 + lr;
#pragma unroll
                for (int j = 0; j < 4; j++) {
                    const int m = m0 + wr * 64 + mf * 16 + lg * 4 + j;
                    outp[(size_t)m * N + n] = f2b(acc[mf][nf][j]);
                }
            }
        return;
    }
#pragma unroll
    for (int mf = 0; mf < 4; mf++) {
#pragma unroll
        for (int nf = 0; nf < 4; nf++) {
            const int n = n0 + wc * 64 + nf * 16 + lr;
            const float bv = bias[n];
#pragma unroll
            for (int j = 0; j < 4; j++) {
                const int m = m0 + wr * 64 + mf * 16 + lg * 4 + j;
                float val = acc[mf][nf][j] + bv;
                if (RESID) val += resid[(size_t)m * N + n];
                if (RELU) val = fmaxf(val, 0.f);
                if (BF16OUT) ((unsigned short*)Cout)[(size_t)m * N + n] = f2b(val);
                else         ((float*)Cout)[(size_t)m * N + n] = val;
            }
        }
    }
}

// ---------------- bf16 MFMA GEMM 64x128, BK=32, counted-vmcnt dbuf ----------------
template<int RELU, int BF16OUT, int RESID>
__global__ __launch_bounds__(256) void k_gemm64(const unsigned short* __restrict__ A,
                                                const unsigned short* __restrict__ Bt,
                                                const float* __restrict__ bias,
                                                const float* __restrict__ resid,
                                                void* __restrict__ Cout,
                                                int M, int N, int K, int ldk, int nbx) {
    __shared__ __align__(16) unsigned short As0[64 * 32];
    __shared__ __align__(16) unsigned short Bs0[128 * 32];
    __shared__ __align__(16) unsigned short As1[64 * 32];
    __shared__ __align__(16) unsigned short Bs1[128 * 32];
    const int tid = threadIdx.x;
    const int cpx = gridDim.x >> 3;
    const int nid = (blockIdx.x & 7) * cpx + (blockIdx.x >> 3);
    const int m0 = (nid / nbx) * 64, n0 = (nid % nbx) * 128;
    const int w = tid >> 6, lane = tid & 63;
    const int wr = w >> 1, wc = w & 1;
    const int lr = lane & 15, lg = lane >> 4;

    f4_t acc[2][4] = {};

    const int r1 = tid >> 2, q1 = tid & 3;
    const unsigned short* pA1 = A + (size_t)(m0 + r1) * ldk + q1 * 8;
    const unsigned short* pB1 = Bt + (size_t)(n0 + r1) * ldk + q1 * 8;
    const unsigned short* pB2 = pB1 + (size_t)64 * ldk;
    const int wofs = w * 512;

#define STAGE(AS, BS, kk) do {                 \
        gll16(pA1 + (kk), (AS) + wofs);        \
        gll16(pB1 + (kk), (BS) + wofs);        \
        gll16(pB2 + (kk), (BS) + 2048 + wofs); } while (0)

#define COMPUTE(AS, BS) do {                                                     \
        bf8_t af[2], bfr[4];                                                     \
        _Pragma("unroll")                                                        \
        for (int f = 0; f < 2; f++)                                              \
            af[f] = *(const bf8_t*)&(AS)[(wr * 32 + f * 16 + lr) * 32 + lg * 8]; \
        _Pragma("unroll")                                                        \
        for (int f = 0; f < 4; f++)                                              \
            bfr[f] = *(const bf8_t*)&(BS)[(wc * 64 + f * 16 + lr) * 32 + lg * 8];\
        _Pragma("unroll")                                                        \
        for (int mf = 0; mf < 2; mf++)                                           \
            _Pragma("unroll")                                                    \
            for (int nf = 0; nf < 4; nf++)                                       \
                acc[mf][nf] = __builtin_amdgcn_mfma_f32_16x16x32_bf16(           \
                    af[mf], bfr[nf], acc[mf][nf], 0, 0, 0); } while (0)

    STAGE(As0, Bs0, 0);
    for (int k0 = 0; k0 + 64 < K; k0 += 64) {
        STAGE(As1, Bs1, k0 + 32);
        VMW(3); BAR();
        COMPUTE(As0, Bs0);
        BAR();
        STAGE(As0, Bs0, k0 + 64);
        VMW(3); BAR();
        COMPUTE(As1, Bs1);
        BAR();
    }
    STAGE(As1, Bs1, K - 32);
    VMW(3); BAR();
    COMPUTE(As0, Bs0);
    VMW(0); BAR();
    COMPUTE(As1, Bs1);
#undef STAGE
#undef COMPUTE

#pragma unroll
    for (int mf = 0; mf < 2; mf++) {
#pragma unroll
        for (int nf = 0; nf < 4; nf++) {
            const int n = n0 + wc * 64 + nf * 16 + lr;
            const float bv = bias[n];
#pragma unroll
            for (int j = 0; j < 4; j++) {
                const int m = m0 + wr * 32 + mf * 16 + lg * 4 + j;
                float val = acc[mf][nf][j] + bv;
                if (RESID) val += resid[(size_t)m * N + n];
                if (RELU) val = fmaxf(val, 0.f);
                if (BF16OUT) ((unsigned short*)Cout)[(size_t)m * N + n] = f2b(val);
                else         ((float*)Cout)[(size_t)m * N + n] = val;
            }
        }
    }
}

// ---------------- FFN2 split-K combine: out = x2 + b2 + p0 + p1 ----------------
__global__ __launch_bounds__(256) void k_comb(const unsigned short* __restrict__ p,
                                              const float* __restrict__ x2,
                                              const float* __restrict__ b2,
                                              float* __restrict__ out) {
    const size_t idx = ((size_t)blockIdx.x * 256 + threadIdx.x) * 8;
    us8_t a = *(const us8_t*)(p + idx);
    us8_t b = *(const us8_t*)(p + (size_t)M_ * D_ + idx);
    const int n = (int)(idx & (D_ - 1));
    f4_t x0 = *(const f4_t*)(x2 + idx), x1 = *(const f4_t*)(x2 + idx + 4);
    f4_t b0 = *(const f4_t*)(b2 + n),  b1 = *(const f4_t*)(b2 + n + 4);
    f4_t o0, o1;
#pragma unroll
    for (int c = 0; c < 4; c++) {
        o0[c] = x0[c] + b0[c] + b2f(a[c]) + b2f(b[c]);
        o1[c] = x1[c] + b1[c] + b2f(a[4 + c]) + b2f(b[4 + c]);
    }
    *(f4_t*)(out + idx) = o0;
    *(f4_t*)(out + idx + 4) = o1;
}

// ---------------- V chunk column sums: sums[bh][c][d] = colsum of chunk c ----------------
__global__ __launch_bounds__(256) void k_vchunksum(const unsigned short* __restrict__ V,
                                                   float* __restrict__ sums) {
    const int blk = blockIdx.x;          // bh*32 + c
    const int bh = blk >> 5, c = blk & 31;
    const int b = bh >> 4, h = bh & 15;
    const int d = threadIdx.x & 63, r4 = threadIdx.x >> 6;
    const unsigned short* base = V + ((size_t)(b * S_ + c * 64 + r4 * 16)) * QKV_STR + h * HD_ + d;
    float s = 0.f;
#pragma unroll
    for (int r = 0; r < 16; r++) s += b2f(base[(size_t)r * QKV_STR]);
    __shared__ float red[4][64];
    red[r4][d] = s;
    __syncthreads();
    if (r4 == 0) sums[(size_t)blk * 64 + d] = red[0][d] + red[1][d] + red[2][d] + red[3][d];
}

// ---------------- exclusive scan of chunk sums -> pre[bh][33][64] ----------------
__global__ __launch_bounds__(64) void k_vscan(const float* __restrict__ sums,
                                              float* __restrict__ pre) {
    const int bh = blockIdx.x, d = threadIdx.x;
    float cum = 0.f;
    for (int c = 0; c < 32; c++) {
        pre[((size_t)bh * 33 + c) * 64 + d] = cum;
        cum += sums[((size_t)bh * 32 + c) * 64 + d];
    }
    pre[((size_t)bh * 33 + 32) * 64 + d] = cum;
}

// ---------------- MFMA flash attention: QBLK=128, fixed-max softmax ----------------
// qblk order within each XCD pairs heavy+light (complementary) so the 2 blocks
// sharing a CU have near-constant total work (tail-balance fix).
#define KS_STRIDE 72   // K tile pad: 64+8

__global__ __launch_bounds__(256) void k_attn_mfma(const unsigned short* __restrict__ QKV,
                                                   const float* __restrict__ vpre,
                                                   unsigned short* __restrict__ Out) {
    __shared__ __align__(16) unsigned short Ks[2][64 * KS_STRIDE];     // [k][d] padded
    __shared__ __align__(16) unsigned short Vt[2][64 * 64];            // [d][kv] chunk-swizzled
    __shared__ __align__(16) unsigned short Ps[4][2][16 * KS_STRIDE];  // per-wave, per-subtile [q][k]

    const int id = blockIdx.x;                   // 512 blocks
    const int wg = (id & 7) * 64 + (id >> 3);    // XCD-chunked bijective swizzle (512%8==0)
    const int v15 = wg & 15;                     // complementary pairing: even->heavy, odd->light
    const int qblk = (v15 & 1) ? ((v15 - 1) >> 1) : (15 - (v15 >> 1));
    const int bh = wg >> 4;
    const int b = bh >> 4, h = bh & 15;
    const int q0 = qblk * 128;
    const int tid = threadIdx.x;
    const int wq = tid >> 6;
    const int lane = tid & 63;
    const int lr = lane & 15, lg = lane >> 4;

    const unsigned short* Qp = QKV;
    const unsigned short* Kp = QKV + 1024;
    const unsigned short* Vp = QKV + 2048;

    const int kcd = 2 * qblk + (wq >> 1);        // wave's diagonal chunk
    const int lastV = 2 * qblk + 1;
    int qb[2];
    qb[0] = (wq & 1) * 32 + lr;
    qb[1] = qb[0] + 16;

    // Q fragments per subtile (B-operand: q = lr), pre-scaled by (1/8)*log2(e)
    bf8_t qfrag[2][2];
#pragma unroll
    for (int t = 0; t < 2; t++) {
        const float qs = 0.125f * 1.44269504f;
        const size_t qbase = ((size_t)(b * S_ + q0 + wq * 32 + t * 16 + lr)) * QKV_STR + h * HD_;
#pragma unroll
        for (int ks = 0; ks < 2; ks++) {
            us8_t raw = *(const us8_t*)(Qp + qbase + ks * 32 + lg * 8);
            ui4_t p;
#pragma unroll
            for (int e = 0; e < 4; e++)
                p[e] = cvt_pk_bf16(b2f(raw[e * 2]) * qs, b2f(raw[e * 2 + 1]) * qs);
            union { ui4_t u; bf8_t b; } c; c.u = p;
            qfrag[t][ks] = c.b;
        }
    }

    // staging geometry
    const int row0 = tid >> 3, g = tid & 7;
    const int row1 = row0 + 32;
    const int r7 = row0 & 7;
    const int wv = tid >> 6;
    const unsigned short* pK0 = Kp + ((size_t)(b * S_ + row0)) * QKV_STR + h * HD_ + g * 8;
    const unsigned short* pK1 = Kp + ((size_t)(b * S_ + row1)) * QKV_STR + h * HD_ + g * 8;
    const unsigned short* pV0 = Vp + ((size_t)(b * S_ + row0)) * QKV_STR + h * HD_ + g * 8;
    const unsigned short* pV1 = Vp + ((size_t)(b * S_ + row1)) * QKV_STR + h * HD_ + g * 8;
    const int sw0 = (wv ^ g) << 3;
    const int sw1 = ((wv + 4) ^ g) << 3;

    float l_run[2] = {0.f, 0.f};
    f4_t acc_o[2][4] = {};
    f4_t acc_pre[2][4] = {};

    // prologue
    ui4_t ck0 = *(const ui4_t*)pK0;
    ui4_t ck1 = *(const ui4_t*)pK1;
    ui4_t cv0 = *(const ui4_t*)pV0;
    ui4_t cv1 = *(const ui4_t*)pV1;
    *(ui4_t*)&Ks[0][row0 * KS_STRIDE + g * 8] = ck0;
    *(ui4_t*)&Ks[0][row1 * KS_STRIDE + g * 8] = ck1;
    {
        const unsigned short* v0 = (const unsigned short*)&cv0;
        const unsigned short* v1 = (const unsigned short*)&cv1;
#pragma unroll
        for (int e = 0; e < 8; e++) {
            const int d = g * 8 + e;
            Vt[0][d * 64 + sw0 + r7] = v0[e];
            Vt[0][d * 64 + sw1 + r7] = v1[e];
        }
    }
    {
        const size_t koff = (size_t)64 * QKV_STR;
        ck0 = *(const ui4_t*)(pK0 + koff);
        ck1 = *(const ui4_t*)(pK1 + koff);
        cv0 = *(const ui4_t*)(pV0 + koff);
        cv1 = *(const ui4_t*)(pV1 + koff);
    }
    __syncthreads();

#define VSLOT(dd, ks) ((((ks) * 4 + lg) ^ (((dd) * 2 + (lr >> 3)) & 7)) << 3)

    for (int kc = 0; kc < 32; kc++) {
        const int cur = kc & 1;
        const unsigned short* Kc = Ks[cur];
        const unsigned short* Vc = Vt[cur];

        // S^T = K·Q^T for both subtiles; K frag read once, used twice
        f4_t s4[2][4] = {};
        __builtin_amdgcn_s_setprio(1);
#pragma unroll
        for (int ks = 0; ks < 2; ks++) {
#pragma unroll
            for (int kk = 0; kk < 4; kk++) {
                bf8_t kfr = *(const bf8_t*)&Kc[(kk * 16 + lr) * KS_STRIDE + ks * 32 + lg * 8];
                s4[0][kk] = __builtin_amdgcn_mfma_f32_16x16x32_bf16(kfr, qfrag[0][ks], s4[0][kk], 0, 0, 0);
                s4[1][kk] = __builtin_amdgcn_mfma_f32_16x16x32_bf16(kfr, qfrag[1][ks], s4[1][kk], 0, 0, 0);
            }
        }
        __builtin_amdgcn_s_setprio(0);

        // stage next chunk (overlaps compute)
        if (kc < 31) {
            unsigned short* Kn = Ks[cur ^ 1];
            *(ui4_t*)&Kn[row0 * KS_STRIDE + g * 8] = ck0;
            *(ui4_t*)&Kn[row1 * KS_STRIDE + g * 8] = ck1;
            if (kc + 1 <= lastV) {
                unsigned short* Vn = Vt[cur ^ 1];
                const unsigned short* v0 = (const unsigned short*)&cv0;
                const unsigned short* v1 = (const unsigned short*)&cv1;
#pragma unroll
                for (int e = 0; e < 8; e++) {
                    const int d = g * 8 + e;
                    Vn[d * 64 + sw0 + r7] = v0[e];
                    Vn[d * 64 + sw1 + r7] = v1[e];
                }
            }
        }
        if (kc < 30) {
            const size_t koff = (size_t)(kc + 2) * 64 * QKV_STR;
            ck0 = *(const ui4_t*)(pK0 + koff);
            ck1 = *(const ui4_t*)(pK1 + koff);
            if (kc + 2 <= lastV) {
                cv0 = *(const ui4_t*)(pV0 + koff);
                cv1 = *(const ui4_t*)(pV1 + koff);
            }
        }

        // fixed-max softmax: p = exp2(s), l += sum(p)
#pragma unroll
        for (int t = 0; t < 2; t++) {
            float cs = 0.f;
#pragma unroll
            for (int kk = 0; kk < 4; kk++)
#pragma unroll
                for (int j = 0; j < 4; j++) {
                    const float p = __builtin_amdgcn_exp2f(s4[t][kk][j]);
                    s4[t][kk][j] = p;
                    cs += p;
                }
            cs += __shfl_xor(cs, 16);
            cs += __shfl_xor(cs, 32);
            l_run[t] += cs;
        }

        if (kc <= kcd) {
            // write P per subtile (masked on wave's diagonal chunk)
#pragma unroll
            for (int t = 0; t < 2; t++) {
                unsigned short* Pw = Ps[wq][t];
#pragma unroll
                for (int kk = 0; kk < 4; kk++) {
                    const int kb = kk * 16 + lg * 4;
                    ui2_t wd;
                    if (kc == kcd) {
                        wd[0] = cvt_pk_bf16(kb + 0 <= qb[t] ? s4[t][kk][0] : 0.f,
                                            kb + 1 <= qb[t] ? s4[t][kk][1] : 0.f);
                        wd[1] = cvt_pk_bf16(kb + 2 <= qb[t] ? s4[t][kk][2] : 0.f,
                                            kb + 3 <= qb[t] ? s4[t][kk][3] : 0.f);
                    } else {
                        wd[0] = cvt_pk_bf16(s4[t][kk][0], s4[t][kk][1]);
                        wd[1] = cvt_pk_bf16(s4[t][kk][2], s4[t][kk][3]);
                    }
                    *(ui2_t*)&Pw[lr * KS_STRIDE + kk * 16 + lg * 4] = wd;
                }
            }
            // O^T += V^T · P^T; V frag read once for both subtiles
            __builtin_amdgcn_s_setprio(1);
#pragma unroll
            for (int ks = 0; ks < 2; ks++) {
                bf8_t pf0 = *(const bf8_t*)&Ps[wq][0][lr * KS_STRIDE + ks * 32 + lg * 8];
                bf8_t pf1 = *(const bf8_t*)&Ps[wq][1][lr * KS_STRIDE + ks * 32 + lg * 8];
#pragma unroll
                for (int dd = 0; dd < 4; dd++) {
                    bf8_t vf = *(const bf8_t*)&Vc[(dd * 16 + lr) * 64 + VSLOT(dd, ks)];
                    acc_o[0][dd] = __builtin_amdgcn_mfma_f32_16x16x32_bf16(vf, pf0, acc_o[0][dd], 0, 0, 0);
                    acc_o[1][dd] = __builtin_amdgcn_mfma_f32_16x16x32_bf16(vf, pf1, acc_o[1][dd], 0, 0, 0);
                }
            }
            __builtin_amdgcn_s_setprio(0);

            if (kc == kcd) {
                // diagonal partial prefix per subtile: P2[q][k] = (k <= q)
#pragma unroll
                for (int t = 0; t < 2; t++) {
                    unsigned short* Pw = Ps[wq][t];
#pragma unroll
                    for (int kk = 0; kk < 4; kk++) {
                        const int kb = kk * 16 + lg * 4;
                        ui2_t wd;
                        wd[0] = (kb + 0 <= qb[t] ? 0x3f80u : 0u) | ((kb + 1 <= qb[t] ? 0x3f80u : 0u) << 16);
                        wd[1] = (kb + 2 <= qb[t] ? 0x3f80u : 0u) | ((kb + 3 <= qb[t] ? 0x3f80u : 0u) << 16);
                        *(ui2_t*)&Pw[lr * KS_STRIDE + kk * 16 + lg * 4] = wd;
                    }
                }
#pragma unroll
                for (int ks = 0; ks < 2; ks++) {
                    bf8_t pf0 = *(const bf8_t*)&Ps[wq][0][lr * KS_STRIDE + ks * 32 + lg * 8];
                    bf8_t pf1 = *(const bf8_t*)&Ps[wq][1][lr * KS_STRIDE + ks * 32 + lg * 8];
#pragma unroll
                    for (int dd = 0; dd < 4; dd++) {
                        bf8_t vf = *(const bf8_t*)&Vc[(dd * 16 + lr) * 64 + VSLOT(dd, ks)];
                        acc_pre[0][dd] = __builtin_amdgcn_mfma_f32_16x16x32_bf16(vf, pf0, acc_pre[0][dd], 0, 0, 0);
                        acc_pre[1][dd] = __builtin_amdgcn_mfma_f32_16x16x32_bf16(vf, pf1, acc_pre[1][dd], 0, 0, 0);
                    }
                }
            }
        }
        __syncthreads();
    }
#undef VSLOT

    // out = O/l - 1e9 * (total - chunkprefix[kcd] - diag_prefix)
    const float* Cq = vpre + ((size_t)bh * 33 + kcd) * 64;
    const float* Ct = vpre + ((size_t)bh * 33 + 32) * 64;
#pragma unroll
    for (int t = 0; t < 2; t++) {
        const float inv_l = 1.f / l_run[t];
        const size_t obase = ((size_t)(b * S_ + q0 + wq * 32 + t * 16 + lr)) * D_ + h * HD_;
#pragma unroll
        for (int dd = 0; dd < 4; dd++) {
            const f4_t tq4 = *(const f4_t*)&Cq[dd * 16 + lg * 4];
            const f4_t tt4 = *(const f4_t*)&Ct[dd * 16 + lg * 4];
            float v[4];
#pragma unroll
            for (int j = 0; j < 4; j++)
                v[j] = acc_o[t][dd][j] * inv_l - 1e9f * (tt4[j] - tq4[j] - acc_pre[t][dd][j]);
            ui2_t wd;
            wd[0] = cvt_pk_bf16(v[0], v[1]);
            wd[1] = cvt_pk_bf16(v[2], v[3]);
            *(ui2_t*)&Out[obase + dd * 16 + lg * 4] = wd;
        }
    }
}

// ---------------- launch ----------------
extern "C" void kernel_launch(void* const* d_in, const int* in_sizes, int n_in,
                              void* d_out, int out_size, void* d_ws, size_t ws_size,
                              hipStream_t stream) {
    const float* x     = (const float*)d_in[0];
    const float* Wq    = (const float*)d_in[1];  const float* bq = (const float*)d_in[2];
    const float* Wk    = (const float*)d_in[3];  const float* bk = (const float*)d_in[4];
    const float* Wv    = (const float*)d_in[5];  const float* bv = (const float*)d_in[6];
    const float* Wo    = (const float*)d_in[7];  const float* bo = (const float*)d_in[8];
    const float* W1    = (const float*)d_in[9];  const float* b1 = (const float*)d_in[10];
    const float* W2    = (const float*)d_in[11]; const float* b2 = (const float*)d_in[12];
    const float* gpre  = (const float*)d_in[13]; const float* bepre  = (const float*)d_in[14];
    const float* gpost = (const float*)d_in[15]; const float* bepost = (const float*)d_in[16];

    char* ws = (char*)d_ws;
    const size_t MB = 1024 * 1024;
    unsigned short* psplit = (unsigned short*)(ws + 0 * MB);   // 16MB, FFN2 partials (over dead weights)
    unsigned short* WqkvT = (unsigned short*)(ws + 0 * MB);    // 6MB   (dead after QKV gemm)
    unsigned short* WoT   = (unsigned short*)(ws + 6 * MB);    // 2MB   (dead after O-proj)
    unsigned short* W1T   = (unsigned short*)(ws + 8 * MB);    // 8MB   (dead after FFN1)
    unsigned short* W2T   = (unsigned short*)(ws + 16 * MB);   // 8MB   (live until FFN2)
    unsigned short* xn    = (unsigned short*)(ws + 24 * MB);   // 8MB   (dead after QKV gemm)
    unsigned short* x2n   = (unsigned short*)(ws + 24 * MB);   // 8MB   (over xn)
    unsigned short* QKV   = (unsigned short*)(ws + 32 * MB);   // 24MB  (dead after attn)
    unsigned short* h1    = (unsigned short*)(ws + 32 * MB);   // 32MB  (over QKV+att)
    unsigned short* att   = (unsigned short*)(ws + 56 * MB);   // 8MB   (dead after O-proj)
    float*          x2    = (float*)(ws + 64 * MB);            // 16MB  (live to end)
    float*          bqkv  = (float*)(ws + 80 * MB);            // 12KB
    float*          vpre  = (float*)(ws + 80 * MB + 16384);    // 270KB
    float*          tab   = (float*)(ws + 80 * MB + 512 * 1024);  // 512KB rope table
    float*          vsum  = (float*)(ws + 81 * MB);            // 256KB

    k_prep<<<12308, 256, 0, stream>>>(Wq, Wk, Wv, Wo, W1, W2, bq, bk, bv,
                                      WqkvT, WoT, W1T, W2T, bqkv, tab);

    k_layernorm<<<M_, 256, 0, stream>>>(x, gpre, bepre, xn);

    // fused QKV projection + bias + RoPE (grid 768, nbx=24)
    k_gemm_bt<0, 1, 0, 1, 0><<<768, 256, 0, stream>>>(xn, WqkvT, bqkv, nullptr, QKV, tab,
                                                      M_, QKV_STR, D_, D_, 24);

    k_vchunksum<<<1024, 256, 0, stream>>>(QKV + 2048, vsum);
    k_vscan<<<32, 64, 0, stream>>>(vsum, vpre);

    k_attn_mfma<<<512, 256, 0, stream>>>(QKV, vpre, att);

    k_gemm64<0, 0, 1><<<512, 256, 0, stream>>>(att, WoT, bo, x, x2, M_, D_, D_, D_, 8);

    k_layernorm<<<M_, 256, 0, stream>>>(x2, gpost, bepost, x2n);

    k_gemm_bt<1, 1, 0, 0, 0><<<1024, 256, 0, stream>>>(x2n, W1T, b1, nullptr, h1, nullptr,
                                                       M_, DFF_, D_, D_, 32);

    // FFN2 split-K=2: grid 512, halves write bf16 partials
    k_gemm_bt<0, 1, 0, 0, 1><<<512, 256, 0, stream>>>(h1, W2T, nullptr, nullptr, psplit, nullptr,
                                                      M_, D_, 2048, DFF_, 8);
    k_comb<<<2048, 256, 0, stream>>>(psplit, x2, b2, (float*)d_out);
}

// Round 16
// 247.491 us; speedup vs baseline: 1.0107x; 1.0107x over previous
//
#include <hip/hip_runtime.h>
#include <stdint.h>

#define B_ 2
#define S_ 2048
#define D_ 1024
#define H_ 16
#define HD_ 64
#define DFF_ 4096
#define M_ 4096        // B*S
#define QKV_STR 3072   // fused QKV row stride

typedef float           f4_t  __attribute__((ext_vector_type(4)));
typedef unsigned int    ui4_t __attribute__((ext_vector_type(4)));
typedef unsigned int    ui2_t __attribute__((ext_vector_type(2)));
typedef unsigned short  us4_t __attribute__((ext_vector_type(4)));
typedef unsigned short  us8_t __attribute__((ext_vector_type(8)));
typedef __bf16          bf8_t __attribute__((ext_vector_type(8)));

__device__ __forceinline__ float b2f(unsigned short u) {
    union { unsigned int u; float f; } v; v.u = ((unsigned int)u) << 16; return v.f;
}
__device__ __forceinline__ unsigned short f2b(float f) {
    union { float f; unsigned int u; } v; v.f = f;
    unsigned int u = v.u + 0x7fffu + ((v.u >> 16) & 1u);
    return (unsigned short)(u >> 16);
}
__device__ __forceinline__ unsigned cvt_pk_bf16(float lo, float hi) {
    unsigned r;
    asm("v_cvt_pk_bf16_f32 %0, %1, %2" : "=v"(r) : "v"(lo), "v"(hi));
    return r;
}
__device__ __forceinline__ void gll16(const unsigned short* g, unsigned short* l) {
    __builtin_amdgcn_global_load_lds((const __attribute__((address_space(1))) unsigned int*)g,
                                     (__attribute__((address_space(3))) unsigned int*)l,
                                     16, 0, 0);
}

// ---------------- fused prep: 6 weight transposes + bias concat + rope table ----------------
__global__ __launch_bounds__(256) void k_prep(const float* __restrict__ Wq, const float* __restrict__ Wk,
                                              const float* __restrict__ Wv, const float* __restrict__ Wo,
                                              const float* __restrict__ W1, const float* __restrict__ W2,
                                              const float* __restrict__ bq, const float* __restrict__ bk,
                                              const float* __restrict__ bv,
                                              unsigned short* __restrict__ WqkvT, unsigned short* __restrict__ WoT,
                                              unsigned short* __restrict__ W1T, unsigned short* __restrict__ W2T,
                                              float* __restrict__ bqkv, float* __restrict__ tab) {
    const int j = blockIdx.x;
    if (j < 12288) {
        const float* src; unsigned short* dst; int R, C, jj;
        if (j < 3072)      { const int r = j >> 10; src = r == 0 ? Wq : (r == 1 ? Wk : Wv);
                             dst = WqkvT + (size_t)r * 1024 * 1024; R = 1024; C = 1024; jj = j & 1023; }
        else if (j < 4096) { src = Wo; dst = WoT; R = 1024; C = 1024; jj = j - 3072; }
        else if (j < 8192) { src = W1; dst = W1T; R = 1024; C = 4096; jj = j - 4096; }
        else               { src = W2; dst = W2T; R = 4096; C = 1024; jj = j - 8192; }
        const int ntx = C >> 5;
        const int bc = (jj % ntx) * 32, br = (jj / ntx) * 32;
        __shared__ float tile[32][33];
        const int tx = threadIdx.x & 31, ty = threadIdx.x >> 5;
#pragma unroll
        for (int i = ty; i < 32; i += 8)
            tile[i][tx] = src[(size_t)(br + i) * C + bc + tx];
        __syncthreads();
#pragma unroll
        for (int i = ty; i < 32; i += 8)
            dst[(size_t)(bc + i) * R + br + tx] = f2b(tile[tx][i]);
    } else if (j < 12300) {
        const int t = (j - 12288) * 256 + threadIdx.x;
        if (t < 1024) bqkv[t] = bq[t];
        else if (t < 2048) bqkv[t] = bk[t - 1024];
        else if (t < 3072) bqkv[t] = bv[t - 2048];
    } else {
        const int base = (j - 12300) * 256 + threadIdx.x;
#pragma unroll
        for (int e = 0; e < 32; e++) {
            const int idx = base + e * 2048;
            const int s = idx >> 5, i = idx & 31;
            const float freq = exp2f(-(float)i * 0.4152410118609203f);
            float sn, cs;
            sincosf((float)s * freq, &sn, &cs);
            tab[s * 64 + i] = cs;
            tab[s * 64 + 32 + i] = sn;
        }
    }
}

// ---------------- layernorm fp32 row(1024) -> bf16 ----------------
__global__ __launch_bounds__(256) void k_layernorm(const float* __restrict__ x,
                                                   const float* __restrict__ g,
                                                   const float* __restrict__ be,
                                                   unsigned short* __restrict__ out) {
    const int row = blockIdx.x;
    const int t = threadIdx.x;
    const float* xr = x + (size_t)row * D_;
    f4_t v = *(const f4_t*)&xr[t * 4];
    float s = v[0] + v[1] + v[2] + v[3];
#pragma unroll
    for (int o = 32; o >= 1; o >>= 1) s += __shfl_down(s, o);
    __shared__ float red[4];
    const int w = t >> 6, lane = t & 63;
    if (lane == 0) red[w] = s;
    __syncthreads();
    const float mean = (red[0] + red[1] + red[2] + red[3]) * (1.f / D_);
    f4_t d;
#pragma unroll
    for (int c = 0; c < 4; c++) d[c] = v[c] - mean;
    float ss = d[0]*d[0] + d[1]*d[1] + d[2]*d[2] + d[3]*d[3];
#pragma unroll
    for (int o = 32; o >= 1; o >>= 1) ss += __shfl_down(ss, o);
    __syncthreads();
    if (lane == 0) red[w] = ss;
    __syncthreads();
    const float var = (red[0] + red[1] + red[2] + red[3]) * (1.f / D_);
    const float rstd = rsqrtf(var + 1e-5f);
    f4_t gv = *(const f4_t*)&g[t * 4];
    f4_t bv = *(const f4_t*)&be[t * 4];
    us4_t o4;
#pragma unroll
    for (int c = 0; c < 4; c++) o4[c] = f2b(d[c] * rstd * gv[c] + bv[c]);
    *(us4_t*)&out[(size_t)row * D_ + t * 4] = o4;
}

#define VMW(n) asm volatile("s_waitcnt vmcnt(" #n ")" ::: "memory")
#define BAR()  __builtin_amdgcn_s_barrier()

// ---------------- bf16 MFMA GEMM 128x128, BK=32, counted-vmcnt dbuf, XCD-chunked 1D grid ----------------
template<int RELU, int BF16OUT, int RESID, int ROPE, int SPLIT>
__global__ __launch_bounds__(256) void k_gemm_bt(const unsigned short* __restrict__ A,
                                                 const unsigned short* __restrict__ Bt,
                                                 const float* __restrict__ bias,
                                                 const float* __restrict__ resid,
                                                 void* __restrict__ Cout,
                                                 const float* __restrict__ tab,
                                                 int M, int N, int K, int ldk, int nbx) {
    __shared__ __align__(16) unsigned short As0[128 * 32];
    __shared__ __align__(16) unsigned short Bs0[128 * 32];
    __shared__ __align__(16) unsigned short As1[128 * 32];
    __shared__ __align__(16) unsigned short Bs1[128 * 32];
    const int tid = threadIdx.x;
    const int cpx = gridDim.x >> 3;
    int nid = (blockIdx.x & 7) * cpx + (blockIdx.x >> 3);
    int half = 0;
    if (SPLIT) { half = nid >> 8; nid &= 255; A += 2048 * half; Bt += 2048 * half; }
    const int m0 = (nid / nbx) * 128, n0 = (nid % nbx) * 128;
    const int w = tid >> 6, lane = tid & 63;
    const int wr = w >> 1, wc = w & 1;
    const int lr = lane & 15, lg = lane >> 4;

    f4_t acc[4][4] = {};

    const int r1 = tid >> 2, q1 = tid & 3;
    const unsigned short* pA1 = A + (size_t)(m0 + r1) * ldk + q1 * 8;
    const unsigned short* pA2 = pA1 + (size_t)64 * ldk;
    const unsigned short* pB1 = Bt + (size_t)(n0 + r1) * ldk + q1 * 8;
    const unsigned short* pB2 = pB1 + (size_t)64 * ldk;
    const int wofs = w * 512;

#define STAGE(AS, BS, kk) do {                 \
        gll16(pA1 + (kk), (AS) + wofs);        \
        gll16(pA2 + (kk), (AS) + 2048 + wofs); \
        gll16(pB1 + (kk), (BS) + wofs);        \
        gll16(pB2 + (kk), (BS) + 2048 + wofs); } while (0)

#define COMPUTE(AS, BS) do {                                                     \
        bf8_t af[4], bfr[4];                                                     \
        _Pragma("unroll")                                                        \
        for (int f = 0; f < 4; f++) {                                            \
            af[f]  = *(const bf8_t*)&(AS)[(wr * 64 + f * 16 + lr) * 32 + lg * 8];\
            bfr[f] = *(const bf8_t*)&(BS)[(wc * 64 + f * 16 + lr) * 32 + lg * 8];\
        }                                                                        \
        _Pragma("unroll")                                                        \
        for (int mf = 0; mf < 4; mf++)                                           \
            _Pragma("unroll")                                                    \
            for (int nf = 0; nf < 4; nf++)                                       \
                acc[mf][nf] = __builtin_amdgcn_mfma_f32_16x16x32_bf16(           \
                    af[mf], bfr[nf], acc[mf][nf], 0, 0, 0); } while (0)

    STAGE(As0, Bs0, 0);
    for (int k0 = 0; k0 + 64 < K; k0 += 64) {
        STAGE(As1, Bs1, k0 + 32);
        VMW(4); BAR();
        COMPUTE(As0, Bs0);
        BAR();
        STAGE(As0, Bs0, k0 + 64);
        VMW(4); BAR();
        COMPUTE(As1, Bs1);
        BAR();
    }
    STAGE(As1, Bs1, K - 32);
    VMW(4); BAR();
    COMPUTE(As0, Bs0);
    VMW(0); BAR();
    COMPUTE(As1, Bs1);
#undef STAGE
#undef COMPUTE

    if (SPLIT) {
        unsigned short* outp = (unsigned short*)Cout + (size_t)half * ((size_t)M * N);
#pragma unroll
        for (int mf = 0; mf < 4; mf++)
#pragma unroll
            for (int nf = 0; nf < 4; nf++) {
                const int n = n0 + wc * 64 + nf * 16 + lr;
#pragma unroll
                for (int j = 0; j < 4; j++) {
                    const int m = m0 + wr * 64 + mf * 16 + lg * 4 + j;
                    outp[(size_t)m * N + n] = f2b(acc[mf][nf][j]);
                }
            }
        return;
    }
    if (ROPE) {
#pragma unroll
        for (int mf = 0; mf < 4; mf++)
#pragma unroll
            for (int nf = 0; nf < 4; nf++) {
                const float bv = bias[n0 + wc * 64 + nf * 16 + lr];
#pragma unroll
                for (int j = 0; j < 4; j++) acc[mf][nf][j] += bv;
            }
        if (n0 < 2048) {
#pragma unroll
            for (int mf = 0; mf < 4; mf++)
#pragma unroll
                for (int j = 0; j < 4; j++) {
                    const int srow = (m0 + wr * 64 + mf * 16 + lg * 4 + j) & 2047;
                    const float* tr = tab + srow * 64;
#pragma unroll
                    for (int t = 0; t < 2; t++) {
                        const float cs = tr[t * 16 + lr];
                        const float sn = tr[32 + t * 16 + lr];
                        const float lo = acc[mf][t][j], hi = acc[mf][t + 2][j];
                        acc[mf][t][j]     = lo * cs - hi * sn;
                        acc[mf][t + 2][j] = hi * cs + lo * sn;
                    }
                }
        }
        unsigned short* outp = (unsigned short*)Cout;
#pragma unroll
        for (int mf = 0; mf < 4; mf++)
#pragma unroll
            for (int nf = 0; nf < 4; nf++) {
                const int n = n0 + wc * 64 + nf * 16 + lr;
#pragma unroll
                for (int j = 0; j < 4; j++) {
                    const int m = m0 + wr * 64 + mf * 16 + lg * 4 + j;
                    outp[(size_t)m * N + n] = f2b(acc[mf][nf][j]);
                }
            }
        return;
    }
#pragma unroll
    for (int mf = 0; mf < 4; mf++) {
#pragma unroll
        for (int nf = 0; nf < 4; nf++) {
            const int n = n0 + wc * 64 + nf * 16 + lr;
            const float bv = bias[n];
#pragma unroll
            for (int j = 0; j < 4; j++) {
                const int m = m0 + wr * 64 + mf * 16 + lg * 4 + j;
                float val = acc[mf][nf][j] + bv;
                if (RESID) val += resid[(size_t)m * N + n];
                if (RELU) val = fmaxf(val, 0.f);
                if (BF16OUT) ((unsigned short*)Cout)[(size_t)m * N + n] = f2b(val);
                else         ((float*)Cout)[(size_t)m * N + n] = val;
            }
        }
    }
}

// ---------------- bf16 MFMA GEMM 64x128, BK=32, counted-vmcnt dbuf ----------------
template<int RELU, int BF16OUT, int RESID>
__global__ __launch_bounds__(256) void k_gemm64(const unsigned short* __restrict__ A,
                                                const unsigned short* __restrict__ Bt,
                                                const float* __restrict__ bias,
                                                const float* __restrict__ resid,
                                                void* __restrict__ Cout,
                                                int M, int N, int K, int ldk, int nbx) {
    __shared__ __align__(16) unsigned short As0[64 * 32];
    __shared__ __align__(16) unsigned short Bs0[128 * 32];
    __shared__ __align__(16) unsigned short As1[64 * 32];
    __shared__ __align__(16) unsigned short Bs1[128 * 32];
    const int tid = threadIdx.x;
    const int cpx = gridDim.x >> 3;
    const int nid = (blockIdx.x & 7) * cpx + (blockIdx.x >> 3);
    const int m0 = (nid / nbx) * 64, n0 = (nid % nbx) * 128;
    const int w = tid >> 6, lane = tid & 63;
    const int wr = w >> 1, wc = w & 1;
    const int lr = lane & 15, lg = lane >> 4;

    f4_t acc[2][4] = {};

    const int r1 = tid >> 2, q1 = tid & 3;
    const unsigned short* pA1 = A + (size_t)(m0 + r1) * ldk + q1 * 8;
    const unsigned short* pB1 = Bt + (size_t)(n0 + r1) * ldk + q1 * 8;
    const unsigned short* pB2 = pB1 + (size_t)64 * ldk;
    const int wofs = w * 512;

#define STAGE(AS, BS, kk) do {                 \
        gll16(pA1 + (kk), (AS) + wofs);        \
        gll16(pB1 + (kk), (BS) + wofs);        \
        gll16(pB2 + (kk), (BS) + 2048 + wofs); } while (0)

#define COMPUTE(AS, BS) do {                                                     \
        bf8_t af[2], bfr[4];                                                     \
        _Pragma("unroll")                                                        \
        for (int f = 0; f < 2; f++)                                              \
            af[f] = *(const bf8_t*)&(AS)[(wr * 32 + f * 16 + lr) * 32 + lg * 8]; \
        _Pragma("unroll")                                                        \
        for (int f = 0; f < 4; f++)                                              \
            bfr[f] = *(const bf8_t*)&(BS)[(wc * 64 + f * 16 + lr) * 32 + lg * 8];\
        _Pragma("unroll")                                                        \
        for (int mf = 0; mf < 2; mf++)                                           \
            _Pragma("unroll")                                                    \
            for (int nf = 0; nf < 4; nf++)                                       \
                acc[mf][nf] = __builtin_amdgcn_mfma_f32_16x16x32_bf16(           \
                    af[mf], bfr[nf], acc[mf][nf], 0, 0, 0); } while (0)

    STAGE(As0, Bs0, 0);
    for (int k0 = 0; k0 + 64 < K; k0 += 64) {
        STAGE(As1, Bs1, k0 + 32);
        VMW(3); BAR();
        COMPUTE(As0, Bs0);
        BAR();
        STAGE(As0, Bs0, k0 + 64);
        VMW(3); BAR();
        COMPUTE(As1, Bs1);
        BAR();
    }
    STAGE(As1, Bs1, K - 32);
    VMW(3); BAR();
    COMPUTE(As0, Bs0);
    VMW(0); BAR();
    COMPUTE(As1, Bs1);
#undef STAGE
#undef COMPUTE

#pragma unroll
    for (int mf = 0; mf < 2; mf++) {
#pragma unroll
        for (int nf = 0; nf < 4; nf++) {
            const int n = n0 + wc * 64 + nf * 16 + lr;
            const float bv = bias[n];
#pragma unroll
            for (int j = 0; j < 4; j++) {
                const int m = m0 + wr * 32 + mf * 16 + lg * 4 + j;
                float val = acc[mf][nf][j] + bv;
                if (RESID) val += resid[(size_t)m * N + n];
                if (RELU) val = fmaxf(val, 0.f);
                if (BF16OUT) ((unsigned short*)Cout)[(size_t)m * N + n] = f2b(val);
                else         ((float*)Cout)[(size_t)m * N + n] = val;
            }
        }
    }
}

// ---------------- FFN2 split-K combine: out = x2 + b2 + p0 + p1 ----------------
__global__ __launch_bounds__(256) void k_comb(const unsigned short* __restrict__ p,
                                              const float* __restrict__ x2,
                                              const float* __restrict__ b2,
                                              float* __restrict__ out) {
    const size_t idx = ((size_t)blockIdx.x * 256 + threadIdx.x) * 8;
    us8_t a = *(const us8_t*)(p + idx);
    us8_t b = *(const us8_t*)(p + (size_t)M_ * D_ + idx);
    const int n = (int)(idx & (D_ - 1));
    f4_t x0 = *(const f4_t*)(x2 + idx), x1 = *(const f4_t*)(x2 + idx + 4);
    f4_t b0 = *(const f4_t*)(b2 + n),  b1 = *(const f4_t*)(b2 + n + 4);
    f4_t o0, o1;
#pragma unroll
    for (int c = 0; c < 4; c++) {
        o0[c] = x0[c] + b0[c] + b2f(a[c]) + b2f(b[c]);
        o1[c] = x1[c] + b1[c] + b2f(a[4 + c]) + b2f(b[4 + c]);
    }
    *(f4_t*)(out + idx) = o0;
    *(f4_t*)(out + idx + 4) = o1;
}

// ---------------- V chunk column sums: sums[bh][c][d] = colsum of chunk c ----------------
__global__ __launch_bounds__(256) void k_vchunksum(const unsigned short* __restrict__ V,
                                                   float* __restrict__ sums) {
    const int blk = blockIdx.x;          // bh*32 + c
    const int bh = blk >> 5, c = blk & 31;
    const int b = bh >> 4, h = bh & 15;
    const int d = threadIdx.x & 63, r4 = threadIdx.x >> 6;
    const unsigned short* base = V + ((size_t)(b * S_ + c * 64 + r4 * 16)) * QKV_STR + h * HD_ + d;
    float s = 0.f;
#pragma unroll
    for (int r = 0; r < 16; r++) s += b2f(base[(size_t)r * QKV_STR]);
    __shared__ float red[4][64];
    red[r4][d] = s;
    __syncthreads();
    if (r4 == 0) sums[(size_t)blk * 64 + d] = red[0][d] + red[1][d] + red[2][d] + red[3][d];
}

// ---------------- exclusive scan of chunk sums -> pre[bh][33][64] ----------------
__global__ __launch_bounds__(64) void k_vscan(const float* __restrict__ sums,
                                              float* __restrict__ pre) {
    const int bh = blockIdx.x, d = threadIdx.x;
    float cum = 0.f;
    for (int c = 0; c < 32; c++) {
        pre[((size_t)bh * 33 + c) * 64 + d] = cum;
        cum += sums[((size_t)bh * 32 + c) * 64 + d];
    }
    pre[((size_t)bh * 33 + 32) * 64 + d] = cum;
}

// ---------------- MFMA flash attention: complementary q-tile pairs, uniform block work ----------------
// Block handles two 64-row q-tiles qA = wg&15, qB = 31-qA (constant total PV work).
// Subtile 0 = tile A, subtile 1 = tile B; wave wq owns rows wq*16..+15 of each.
#define KS_STRIDE 72   // K tile pad: 64+8

__global__ __launch_bounds__(256) void k_attn_mfma(const unsigned short* __restrict__ QKV,
                                                   const float* __restrict__ vpre,
                                                   unsigned short* __restrict__ Out) {
    __shared__ __align__(16) unsigned short Ks[2][64 * KS_STRIDE];     // [k][d] padded
    __shared__ __align__(16) unsigned short Vt[2][64 * 64];            // [d][kv] chunk-swizzled
    __shared__ __align__(16) unsigned short Ps[4][2][16 * KS_STRIDE];  // per-wave, per-subtile [q][k]

    const int id = blockIdx.x;                   // 512 blocks
    const int wg = (id & 7) * 64 + (id >> 3);    // XCD-chunked bijective swizzle (512%8==0)
    const int qA = wg & 15;                      // tile A chunk index (0..15)
    const int qB = 31 - qA;                      // tile B chunk index (16..31)
    const int bh = wg >> 4;
    const int b = bh >> 4, h = bh & 15;
    const int tid = threadIdx.x;
    const int wq = tid >> 6;
    const int lane = tid & 63;
    const int lr = lane & 15, lg = lane >> 4;

    const unsigned short* Qp = QKV;
    const unsigned short* Kp = QKV + 1024;
    const unsigned short* Vp = QKV + 2048;

    const int kcdt[2] = {qA, qB};                // per-subtile diagonal chunk (block-uniform)
    const int lastV = qB;                        // V staging horizon
    const int qb = wq * 16 + lr;                 // row within diagonal chunk (both subtiles)
    const int q0t[2] = {qA * 64, qB * 64};

    // Q fragments per subtile (B-operand: q = lr), pre-scaled by (1/8)*log2(e)
    bf8_t qfrag[2][2];
#pragma unroll
    for (int t = 0; t < 2; t++) {
        const float qs = 0.125f * 1.44269504f;
        const size_t qbase = ((size_t)(b * S_ + q0t[t] + wq * 16 + lr)) * QKV_STR + h * HD_;
#pragma unroll
        for (int ks = 0; ks < 2; ks++) {
            us8_t raw = *(const us8_t*)(Qp + qbase + ks * 32 + lg * 8);
            ui4_t p;
#pragma unroll
            for (int e = 0; e < 4; e++)
                p[e] = cvt_pk_bf16(b2f(raw[e * 2]) * qs, b2f(raw[e * 2 + 1]) * qs);
            union { ui4_t u; bf8_t b; } c; c.u = p;
            qfrag[t][ks] = c.b;
        }
    }

    // staging geometry
    const int row0 = tid >> 3, g = tid & 7;
    const int row1 = row0 + 32;
    const int r7 = row0 & 7;
    const int wv = tid >> 6;
    const unsigned short* pK0 = Kp + ((size_t)(b * S_ + row0)) * QKV_STR + h * HD_ + g * 8;
    const unsigned short* pK1 = Kp + ((size_t)(b * S_ + row1)) * QKV_STR + h * HD_ + g * 8;
    const unsigned short* pV0 = Vp + ((size_t)(b * S_ + row0)) * QKV_STR + h * HD_ + g * 8;
    const unsigned short* pV1 = Vp + ((size_t)(b * S_ + row1)) * QKV_STR + h * HD_ + g * 8;
    const int sw0 = (wv ^ g) << 3;
    const int sw1 = ((wv + 4) ^ g) << 3;

    float l_run[2] = {0.f, 0.f};
    f4_t acc_o[2][4] = {};
    f4_t acc_pre[2][4] = {};

    // prologue
    ui4_t ck0 = *(const ui4_t*)pK0;
    ui4_t ck1 = *(const ui4_t*)pK1;
    ui4_t cv0 = *(const ui4_t*)pV0;
    ui4_t cv1 = *(const ui4_t*)pV1;
    *(ui4_t*)&Ks[0][row0 * KS_STRIDE + g * 8] = ck0;
    *(ui4_t*)&Ks[0][row1 * KS_STRIDE + g * 8] = ck1;
    {
        const unsigned short* v0 = (const unsigned short*)&cv0;
        const unsigned short* v1 = (const unsigned short*)&cv1;
#pragma unroll
        for (int e = 0; e < 8; e++) {
            const int d = g * 8 + e;
            Vt[0][d * 64 + sw0 + r7] = v0[e];
            Vt[0][d * 64 + sw1 + r7] = v1[e];
        }
    }
    {
        const size_t koff = (size_t)64 * QKV_STR;
        ck0 = *(const ui4_t*)(pK0 + koff);
        ck1 = *(const ui4_t*)(pK1 + koff);
        cv0 = *(const ui4_t*)(pV0 + koff);
        cv1 = *(const ui4_t*)(pV1 + koff);
    }
    __syncthreads();

#define VSLOT(dd, ks) ((((ks) * 4 + lg) ^ (((dd) * 2 + (lr >> 3)) & 7)) << 3)

    for (int kc = 0; kc < 32; kc++) {
        const int cur = kc & 1;
        const unsigned short* Kc = Ks[cur];
        const unsigned short* Vc = Vt[cur];

        // S^T = K·Q^T for both subtiles; K frag read once, used twice
        f4_t s4[2][4] = {};
        __builtin_amdgcn_s_setprio(1);
#pragma unroll
        for (int ks = 0; ks < 2; ks++) {
#pragma unroll
            for (int kk = 0; kk < 4; kk++) {
                bf8_t kfr = *(const bf8_t*)&Kc[(kk * 16 + lr) * KS_STRIDE + ks * 32 + lg * 8];
                s4[0][kk] = __builtin_amdgcn_mfma_f32_16x16x32_bf16(kfr, qfrag[0][ks], s4[0][kk], 0, 0, 0);
                s4[1][kk] = __builtin_amdgcn_mfma_f32_16x16x32_bf16(kfr, qfrag[1][ks], s4[1][kk], 0, 0, 0);
            }
        }
        __builtin_amdgcn_s_setprio(0);

        // stage next chunk (overlaps compute)
        if (kc < 31) {
            unsigned short* Kn = Ks[cur ^ 1];
            *(ui4_t*)&Kn[row0 * KS_STRIDE + g * 8] = ck0;
            *(ui4_t*)&Kn[row1 * KS_STRIDE + g * 8] = ck1;
            if (kc + 1 <= lastV) {
                unsigned short* Vn = Vt[cur ^ 1];
                const unsigned short* v0 = (const unsigned short*)&cv0;
                const unsigned short* v1 = (const unsigned short*)&cv1;
#pragma unroll
                for (int e = 0; e < 8; e++) {
                    const int d = g * 8 + e;
                    Vn[d * 64 + sw0 + r7] = v0[e];
                    Vn[d * 64 + sw1 + r7] = v1[e];
                }
            }
        }
        if (kc < 30) {
            const size_t koff = (size_t)(kc + 2) * 64 * QKV_STR;
            ck0 = *(const ui4_t*)(pK0 + koff);
            ck1 = *(const ui4_t*)(pK1 + koff);
            if (kc + 2 <= lastV) {
                cv0 = *(const ui4_t*)(pV0 + koff);
                cv1 = *(const ui4_t*)(pV1 + koff);
            }
        }

        // fixed-max softmax: p = exp2(s), l += sum(p)
#pragma unroll
        for (int t = 0; t < 2; t++) {
            float cs = 0.f;
#pragma unroll
            for (int kk = 0; kk < 4; kk++)
#pragma unroll
                for (int j = 0; j < 4; j++) {
                    const float p = __builtin_amdgcn_exp2f(s4[t][kk][j]);
                    s4[t][kk][j] = p;
                    cs += p;
                }
            cs += __shfl_xor(cs, 16);
            cs += __shfl_xor(cs, 32);
            l_run[t] += cs;
        }

        if (kc <= qB) {                     // V staged & needed by at least subtile 1
            const bool doA = (kc <= qA);
            // write P: subtile 1 always (masked at its diagonal), subtile 0 if active
#pragma unroll
            for (int kk = 0; kk < 4; kk++) {
                const int kb = kk * 16 + lg * 4;
                ui2_t wd;
                if (kc == qB) {
                    wd[0] = cvt_pk_bf16(kb + 0 <= qb ? s4[1][kk][0] : 0.f,
                                        kb + 1 <= qb ? s4[1][kk][1] : 0.f);
                    wd[1] = cvt_pk_bf16(kb + 2 <= qb ? s4[1][kk][2] : 0.f,
                                        kb + 3 <= qb ? s4[1][kk][3] : 0.f);
                } else {
                    wd[0] = cvt_pk_bf16(s4[1][kk][0], s4[1][kk][1]);
                    wd[1] = cvt_pk_bf16(s4[1][kk][2], s4[1][kk][3]);
                }
                *(ui2_t*)&Ps[wq][1][lr * KS_STRIDE + kk * 16 + lg * 4] = wd;
            }
            if (doA) {
#pragma unroll
                for (int kk = 0; kk < 4; kk++) {
                    const int kb = kk * 16 + lg * 4;
                    ui2_t wd;
                    if (kc == qA) {
                        wd[0] = cvt_pk_bf16(kb + 0 <= qb ? s4[0][kk][0] : 0.f,
                                            kb + 1 <= qb ? s4[0][kk][1] : 0.f);
                        wd[1] = cvt_pk_bf16(kb + 2 <= qb ? s4[0][kk][2] : 0.f,
                                            kb + 3 <= qb ? s4[0][kk][3] : 0.f);
                    } else {
                        wd[0] = cvt_pk_bf16(s4[0][kk][0], s4[0][kk][1]);
                        wd[1] = cvt_pk_bf16(s4[0][kk][2], s4[0][kk][3]);
                    }
                    *(ui2_t*)&Ps[wq][0][lr * KS_STRIDE + kk * 16 + lg * 4] = wd;
                }
            }
            // O^T += V^T · P^T; V frag read once, used by active subtiles
            __builtin_amdgcn_s_setprio(1);
#pragma unroll
            for (int ks = 0; ks < 2; ks++) {
                bf8_t pf1 = *(const bf8_t*)&Ps[wq][1][lr * KS_STRIDE + ks * 32 + lg * 8];
                bf8_t pf0;
                if (doA) pf0 = *(const bf8_t*)&Ps[wq][0][lr * KS_STRIDE + ks * 32 + lg * 8];
#pragma unroll
                for (int dd = 0; dd < 4; dd++) {
                    bf8_t vf = *(const bf8_t*)&Vc[(dd * 16 + lr) * 64 + VSLOT(dd, ks)];
                    acc_o[1][dd] = __builtin_amdgcn_mfma_f32_16x16x32_bf16(vf, pf1, acc_o[1][dd], 0, 0, 0);
                    if (doA)
                        acc_o[0][dd] = __builtin_amdgcn_mfma_f32_16x16x32_bf16(vf, pf0, acc_o[0][dd], 0, 0, 0);
                }
            }
            __builtin_amdgcn_s_setprio(0);

            // diagonal partial prefix (subtile-specific kc)
#pragma unroll
            for (int t = 0; t < 2; t++) {
                if (kc == kcdt[t]) {
                    unsigned short* Pw = Ps[wq][t];
#pragma unroll
                    for (int kk = 0; kk < 4; kk++) {
                        const int kb = kk * 16 + lg * 4;
                        ui2_t wd;
                        wd[0] = (kb + 0 <= qb ? 0x3f80u : 0u) | ((kb + 1 <= qb ? 0x3f80u : 0u) << 16);
                        wd[1] = (kb + 2 <= qb ? 0x3f80u : 0u) | ((kb + 3 <= qb ? 0x3f80u : 0u) << 16);
                        *(ui2_t*)&Pw[lr * KS_STRIDE + kk * 16 + lg * 4] = wd;
                    }
#pragma unroll
                    for (int ks = 0; ks < 2; ks++) {
                        bf8_t pf = *(const bf8_t*)&Pw[lr * KS_STRIDE + ks * 32 + lg * 8];
#pragma unroll
                        for (int dd = 0; dd < 4; dd++) {
                            bf8_t vf = *(const bf8_t*)&Vc[(dd * 16 + lr) * 64 + VSLOT(dd, ks)];
                            acc_pre[t][dd] = __builtin_amdgcn_mfma_f32_16x16x32_bf16(vf, pf, acc_pre[t][dd], 0, 0, 0);
                        }
                    }
                }
            }
        }
        __syncthreads();
    }
#undef VSLOT

    // out = O/l - 1e9 * (total - chunkprefix[kcd_t] - diag_prefix)
    const float* Ct = vpre + ((size_t)bh * 33 + 32) * 64;
#pragma unroll
    for (int t = 0; t < 2; t++) {
        const float* Cq = vpre + ((size_t)bh * 33 + kcdt[t]) * 64;
        const float inv_l = 1.f / l_run[t];
        const size_t obase = ((size_t)(b * S_ + q0t[t] + wq * 16 + lr)) * D_ + h * HD_;
#pragma unroll
        for (int dd = 0; dd < 4; dd++) {
            const f4_t tq4 = *(const f4_t*)&Cq[dd * 16 + lg * 4];
            const f4_t tt4 = *(const f4_t*)&Ct[dd * 16 + lg * 4];
            float v[4];
#pragma unroll
            for (int j = 0; j < 4; j++)
                v[j] = acc_o[t][dd][j] * inv_l - 1e9f * (tt4[j] - tq4[j] - acc_pre[t][dd][j]);
            ui2_t wd;
            wd[0] = cvt_pk_bf16(v[0], v[1]);
            wd[1] = cvt_pk_bf16(v[2], v[3]);
            *(ui2_t*)&Out[obase + dd * 16 + lg * 4] = wd;
        }
    }
}

// ---------------- launch ----------------
extern "C" void kernel_launch(void* const* d_in, const int* in_sizes, int n_in,
                              void* d_out, int out_size, void* d_ws, size_t ws_size,
                              hipStream_t stream) {
    const float* x     = (const float*)d_in[0];
    const float* Wq    = (const float*)d_in[1];  const float* bq = (const float*)d_in[2];
    const float* Wk    = (const float*)d_in[3];  const float* bk = (const float*)d_in[4];
    const float* Wv    = (const float*)d_in[5];  const float* bv = (const float*)d_in[6];
    const float* Wo    = (const float*)d_in[7];  const float* bo = (const float*)d_in[8];
    const float* W1    = (const float*)d_in[9];  const float* b1 = (const float*)d_in[10];
    const float* W2    = (const float*)d_in[11]; const float* b2 = (const float*)d_in[12];
    const float* gpre  = (const float*)d_in[13]; const float* bepre  = (const float*)d_in[14];
    const float* gpost = (const float*)d_in[15]; const float* bepost = (const float*)d_in[16];

    char* ws = (char*)d_ws;
    const size_t MB = 1024 * 1024;
    unsigned short* psplit = (unsigned short*)(ws + 0 * MB);   // 16MB, FFN2 partials (over dead weights)
    unsigned short* WqkvT = (unsigned short*)(ws + 0 * MB);    // 6MB   (dead after QKV gemm)
    unsigned short* WoT   = (unsigned short*)(ws + 6 * MB);    // 2MB   (dead after O-proj)
    unsigned short* W1T   = (unsigned short*)(ws + 8 * MB);    // 8MB   (dead after FFN1)
    unsigned short* W2T   = (unsigned short*)(ws + 16 * MB);   // 8MB   (live until FFN2)
    unsigned short* xn    = (unsigned short*)(ws + 24 * MB);   // 8MB   (dead after QKV gemm)
    unsigned short* x2n   = (unsigned short*)(ws + 24 * MB);   // 8MB   (over xn)
    unsigned short* QKV   = (unsigned short*)(ws + 32 * MB);   // 24MB  (dead after attn)
    unsigned short* h1    = (unsigned short*)(ws + 32 * MB);   // 32MB  (over QKV+att)
    unsigned short* att   = (unsigned short*)(ws + 56 * MB);   // 8MB   (dead after O-proj)
    float*          x2    = (float*)(ws + 64 * MB);            // 16MB  (live to end)
    float*          bqkv  = (float*)(ws + 80 * MB);            // 12KB
    float*          vpre  = (float*)(ws + 80 * MB + 16384);    // 270KB
    float*          tab   = (float*)(ws + 80 * MB + 512 * 1024);  // 512KB rope table
    float*          vsum  = (float*)(ws + 81 * MB);            // 256KB

    k_prep<<<12308, 256, 0, stream>>>(Wq, Wk, Wv, Wo, W1, W2, bq, bk, bv,
                                      WqkvT, WoT, W1T, W2T, bqkv, tab);

    k_layernorm<<<M_, 256, 0, stream>>>(x, gpre, bepre, xn);

    // fused QKV projection + bias + RoPE (grid 768, nbx=24)
    k_gemm_bt<0, 1, 0, 1, 0><<<768, 256, 0, stream>>>(xn, WqkvT, bqkv, nullptr, QKV, tab,
                                                      M_, QKV_STR, D_, D_, 24);

    k_vchunksum<<<1024, 256, 0, stream>>>(QKV + 2048, vsum);
    k_vscan<<<32, 64, 0, stream>>>(vsum, vpre);

    k_attn_mfma<<<512, 256, 0, stream>>>(QKV, vpre, att);

    k_gemm64<0, 0, 1><<<512, 256, 0, stream>>>(att, WoT, bo, x, x2, M_, D_, D_, D_, 8);

    k_layernorm<<<M_, 256, 0, stream>>>(x2, gpost, bepost, x2n);

    k_gemm_bt<1, 1, 0, 0, 0><<<1024, 256, 0, stream>>>(x2n, W1T, b1, nullptr, h1, nullptr,
                                                       M_, DFF_, D_, D_, 32);

    // FFN2 split-K=2: grid 512, halves write bf16 partials
    k_gemm_bt<0, 1, 0, 0, 1><<<512, 256, 0, stream>>>(h1, W2T, nullptr, nullptr, psplit, nullptr,
                                                      M_, D_, 2048, DFF_, 8);
    k_comb<<<2048, 256, 0, stream>>>(psplit, x2, b2, (float*)d_out);
}

// Round 17
// 243.912 us; speedup vs baseline: 1.0255x; 1.0147x over previous
//
#include <hip/hip_runtime.h>
#include <stdint.h>

#define B_ 2
#define S_ 2048
#define D_ 1024
#define H_ 16
#define HD_ 64
#define DFF_ 4096
#define M_ 4096        // B*S
#define QKV_STR 3072   // fused QKV row stride

typedef float           f4_t  __attribute__((ext_vector_type(4)));
typedef unsigned int    ui4_t __attribute__((ext_vector_type(4)));
typedef unsigned int    ui2_t __attribute__((ext_vector_type(2)));
typedef unsigned short  us4_t __attribute__((ext_vector_type(4)));
typedef unsigned short  us8_t __attribute__((ext_vector_type(8)));
typedef __bf16          bf8_t __attribute__((ext_vector_type(8)));

__device__ __forceinline__ float b2f(unsigned short u) {
    union { unsigned int u; float f; } v; v.u = ((unsigned int)u) << 16; return v.f;
}
__device__ __forceinline__ unsigned short f2b(float f) {
    union { float f; unsigned int u; } v; v.f = f;
    unsigned int u = v.u + 0x7fffu + ((v.u >> 16) & 1u);
    return (unsigned short)(u >> 16);
}
__device__ __forceinline__ unsigned cvt_pk_bf16(float lo, float hi) {
    unsigned r;
    asm("v_cvt_pk_bf16_f32 %0, %1, %2" : "=v"(r) : "v"(lo), "v"(hi));
    return r;
}
__device__ __forceinline__ void gll16(const unsigned short* g, unsigned short* l) {
    __builtin_amdgcn_global_load_lds((const __attribute__((address_space(1))) unsigned int*)g,
                                     (__attribute__((address_space(3))) unsigned int*)l,
                                     16, 0, 0);
}

// ---------------- fused prep: 6 weight transposes + bias concat + rope table ----------------
__global__ __launch_bounds__(256) void k_prep(const float* __restrict__ Wq, const float* __restrict__ Wk,
                                              const float* __restrict__ Wv, const float* __restrict__ Wo,
                                              const float* __restrict__ W1, const float* __restrict__ W2,
                                              const float* __restrict__ bq, const float* __restrict__ bk,
                                              const float* __restrict__ bv,
                                              unsigned short* __restrict__ WqkvT, unsigned short* __restrict__ WoT,
                                              unsigned short* __restrict__ W1T, unsigned short* __restrict__ W2T,
                                              float* __restrict__ bqkv, float* __restrict__ tab) {
    const int j = blockIdx.x;
    if (j < 12288) {
        const float* src; unsigned short* dst; int R, C, jj;
        if (j < 3072)      { const int r = j >> 10; src = r == 0 ? Wq : (r == 1 ? Wk : Wv);
                             dst = WqkvT + (size_t)r * 1024 * 1024; R = 1024; C = 1024; jj = j & 1023; }
        else if (j < 4096) { src = Wo; dst = WoT; R = 1024; C = 1024; jj = j - 3072; }
        else if (j < 8192) { src = W1; dst = W1T; R = 1024; C = 4096; jj = j - 4096; }
        else               { src = W2; dst = W2T; R = 4096; C = 1024; jj = j - 8192; }
        const int ntx = C >> 5;
        const int bc = (jj % ntx) * 32, br = (jj / ntx) * 32;
        __shared__ float tile[32][33];
        const int tx = threadIdx.x & 31, ty = threadIdx.x >> 5;
#pragma unroll
        for (int i = ty; i < 32; i += 8)
            tile[i][tx] = src[(size_t)(br + i) * C + bc + tx];
        __syncthreads();
#pragma unroll
        for (int i = ty; i < 32; i += 8)
            dst[(size_t)(bc + i) * R + br + tx] = f2b(tile[tx][i]);
    } else if (j < 12300) {
        const int t = (j - 12288) * 256 + threadIdx.x;
        if (t < 1024) bqkv[t] = bq[t];
        else if (t < 2048) bqkv[t] = bk[t - 1024];
        else if (t < 3072) bqkv[t] = bv[t - 2048];
    } else {
        const int base = (j - 12300) * 256 + threadIdx.x;
#pragma unroll
        for (int e = 0; e < 32; e++) {
            const int idx = base + e * 2048;
            const int s = idx >> 5, i = idx & 31;
            const float freq = exp2f(-(float)i * 0.4152410118609203f);
            float sn, cs;
            sincosf((float)s * freq, &sn, &cs);
            tab[s * 64 + i] = cs;
            tab[s * 64 + 32 + i] = sn;
        }
    }
}

// ---------------- layernorm fp32 row(1024) -> bf16 ----------------
__global__ __launch_bounds__(256) void k_layernorm(const float* __restrict__ x,
                                                   const float* __restrict__ g,
                                                   const float* __restrict__ be,
                                                   unsigned short* __restrict__ out) {
    const int row = blockIdx.x;
    const int t = threadIdx.x;
    const float* xr = x + (size_t)row * D_;
    f4_t v = *(const f4_t*)&xr[t * 4];
    float s = v[0] + v[1] + v[2] + v[3];
#pragma unroll
    for (int o = 32; o >= 1; o >>= 1) s += __shfl_down(s, o);
    __shared__ float red[4];
    const int w = t >> 6, lane = t & 63;
    if (lane == 0) red[w] = s;
    __syncthreads();
    const float mean = (red[0] + red[1] + red[2] + red[3]) * (1.f / D_);
    f4_t d;
#pragma unroll
    for (int c = 0; c < 4; c++) d[c] = v[c] - mean;
    float ss = d[0]*d[0] + d[1]*d[1] + d[2]*d[2] + d[3]*d[3];
#pragma unroll
    for (int o = 32; o >= 1; o >>= 1) ss += __shfl_down(ss, o);
    __syncthreads();
    if (lane == 0) red[w] = ss;
    __syncthreads();
    const float var = (red[0] + red[1] + red[2] + red[3]) * (1.f / D_);
    const float rstd = rsqrtf(var + 1e-5f);
    f4_t gv = *(const f4_t*)&g[t * 4];
    f4_t bv = *(const f4_t*)&be[t * 4];
    us4_t o4;
#pragma unroll
    for (int c = 0; c < 4; c++) o4[c] = f2b(d[c] * rstd * gv[c] + bv[c]);
    *(us4_t*)&out[(size_t)row * D_ + t * 4] = o4;
}

#define VMW(n) asm volatile("s_waitcnt vmcnt(" #n ")" ::: "memory")
#define BAR()  __builtin_amdgcn_s_barrier()

// ---------------- bf16 MFMA GEMM 128x128, BK=32, counted-vmcnt dbuf, XCD-chunked 1D grid ----------------
template<int RELU, int BF16OUT, int RESID, int ROPE, int SPLIT>
__global__ __launch_bounds__(256) void k_gemm_bt(const unsigned short* __restrict__ A,
                                                 const unsigned short* __restrict__ Bt,
                                                 const float* __restrict__ bias,
                                                 const float* __restrict__ resid,
                                                 void* __restrict__ Cout,
                                                 const float* __restrict__ tab,
                                                 int M, int N, int K, int ldk, int nbx) {
    __shared__ __align__(16) unsigned short As0[128 * 32];
    __shared__ __align__(16) unsigned short Bs0[128 * 32];
    __shared__ __align__(16) unsigned short As1[128 * 32];
    __shared__ __align__(16) unsigned short Bs1[128 * 32];
    const int tid = threadIdx.x;
    const int cpx = gridDim.x >> 3;
    int nid = (blockIdx.x & 7) * cpx + (blockIdx.x >> 3);
    int half = 0;
    if (SPLIT) { half = nid >> 8; nid &= 255; A += 2048 * half; Bt += 2048 * half; }
    const int m0 = (nid / nbx) * 128, n0 = (nid % nbx) * 128;
    const int w = tid >> 6, lane = tid & 63;
    const int wr = w >> 1, wc = w & 1;
    const int lr = lane & 15, lg = lane >> 4;

    f4_t acc[4][4] = {};

    const int r1 = tid >> 2, q1 = tid & 3;
    const unsigned short* pA1 = A + (size_t)(m0 + r1) * ldk + q1 * 8;
    const unsigned short* pA2 = pA1 + (size_t)64 * ldk;
    const unsigned short* pB1 = Bt + (size_t)(n0 + r1) * ldk + q1 * 8;
    const unsigned short* pB2 = pB1 + (size_t)64 * ldk;
    const int wofs = w * 512;

#define STAGE(AS, BS, kk) do {                 \
        gll16(pA1 + (kk), (AS) + wofs);        \
        gll16(pA2 + (kk), (AS) + 2048 + wofs); \
        gll16(pB1 + (kk), (BS) + wofs);        \
        gll16(pB2 + (kk), (BS) + 2048 + wofs); } while (0)

#define COMPUTE(AS, BS) do {                                                     \
        bf8_t af[4], bfr[4];                                                     \
        _Pragma("unroll")                                                        \
        for (int f = 0; f < 4; f++) {                                            \
            af[f]  = *(const bf8_t*)&(AS)[(wr * 64 + f * 16 + lr) * 32 + lg * 8];\
            bfr[f] = *(const bf8_t*)&(BS)[(wc * 64 + f * 16 + lr) * 32 + lg * 8];\
        }                                                                        \
        _Pragma("unroll")                                                        \
        for (int mf = 0; mf < 4; mf++)                                           \
            _Pragma("unroll")                                                    \
            for (int nf = 0; nf < 4; nf++)                                       \
                acc[mf][nf] = __builtin_amdgcn_mfma_f32_16x16x32_bf16(           \
                    af[mf], bfr[nf], acc[mf][nf], 0, 0, 0); } while (0)

    STAGE(As0, Bs0, 0);
    for (int k0 = 0; k0 + 64 < K; k0 += 64) {
        STAGE(As1, Bs1, k0 + 32);
        VMW(4); BAR();
        COMPUTE(As0, Bs0);
        BAR();
        STAGE(As0, Bs0, k0 + 64);
        VMW(4); BAR();
        COMPUTE(As1, Bs1);
        BAR();
    }
    STAGE(As1, Bs1, K - 32);
    VMW(4); BAR();
    COMPUTE(As0, Bs0);
    VMW(0); BAR();
    COMPUTE(As1, Bs1);
#undef STAGE
#undef COMPUTE

    if (SPLIT) {
        unsigned short* outp = (unsigned short*)Cout + (size_t)half * ((size_t)M * N);
#pragma unroll
        for (int mf = 0; mf < 4; mf++)
#pragma unroll
            for (int nf = 0; nf < 4; nf++) {
                const int n = n0 + wc * 64 + nf * 16 + lr;
#pragma unroll
                for (int j = 0; j < 4; j++) {
                    const int m = m0 + wr * 64 + mf * 16 + lg * 4 + j;
                    outp[(size_t)m * N + n] = f2b(acc[mf][nf][j]);
                }
            }
        return;
    }
    if (ROPE) {
#pragma unroll
        for (int mf = 0; mf < 4; mf++)
#pragma unroll
            for (int nf = 0; nf < 4; nf++) {
                const float bv = bias[n0 + wc * 64 + nf * 16 + lr];
#pragma unroll
                for (int j = 0; j < 4; j++) acc[mf][nf][j] += bv;
            }
        if (n0 < 2048) {
#pragma unroll
            for (int mf = 0; mf < 4; mf++)
#pragma unroll
                for (int j = 0; j < 4; j++) {
                    const int srow = (m0 + wr * 64 + mf * 16 + lg * 4 + j) & 2047;
                    const float* tr = tab + srow * 64;
#pragma unroll
                    for (int t = 0; t < 2; t++) {
                        const float cs = tr[t * 16 + lr];
                        const float sn = tr[32 + t * 16 + lr];
                        const float lo = acc[mf][t][j], hi = acc[mf][t + 2][j];
                        acc[mf][t][j]     = lo * cs - hi * sn;
                        acc[mf][t + 2][j] = hi * cs + lo * sn;
                    }
                }
        }
        unsigned short* outp = (unsigned short*)Cout;
#pragma unroll
        for (int mf = 0; mf < 4; mf++)
#pragma unroll
            for (int nf = 0; nf < 4; nf++) {
                const int n = n0 + wc * 64 + nf * 16 + lr;
#pragma unroll
                for (int j = 0; j < 4; j++) {
                    const int m = m0 + wr * 64 + mf * 16 + lg * 4 + j;
                    outp[(size_t)m * N + n] = f2b(acc[mf][nf][j]);
                }
            }
        return;
    }
#pragma unroll
    for (int mf = 0; mf < 4; mf++) {
#pragma unroll
        for (int nf = 0; nf < 4; nf++) {
            const int n = n0 + wc * 64 + nf * 16 + lr;
            const float bv = bias[n];
#pragma unroll
            for (int j = 0; j < 4; j++) {
                const int m = m0 + wr * 64 + mf * 16 + lg * 4 + j;
                float val = acc[mf][nf][j] + bv;
                if (RESID) val += resid[(size_t)m * N + n];
                if (RELU) val = fmaxf(val, 0.f);
                if (BF16OUT) ((unsigned short*)Cout)[(size_t)m * N + n] = f2b(val);
                else         ((float*)Cout)[(size_t)m * N + n] = val;
            }
        }
    }
}

// ---------------- bf16 MFMA GEMM 64x128, BK=32, counted-vmcnt dbuf ----------------
template<int RELU, int BF16OUT, int RESID>
__global__ __launch_bounds__(256) void k_gemm64(const unsigned short* __restrict__ A,
                                                const unsigned short* __restrict__ Bt,
                                                const float* __restrict__ bias,
                                                const float* __restrict__ resid,
                                                void* __restrict__ Cout,
                                                int M, int N, int K, int ldk, int nbx) {
    __shared__ __align__(16) unsigned short As0[64 * 32];
    __shared__ __align__(16) unsigned short Bs0[128 * 32];
    __shared__ __align__(16) unsigned short As1[64 * 32];
    __shared__ __align__(16) unsigned short Bs1[128 * 32];
    const int tid = threadIdx.x;
    const int cpx = gridDim.x >> 3;
    const int nid = (blockIdx.x & 7) * cpx + (blockIdx.x >> 3);
    const int m0 = (nid / nbx) * 64, n0 = (nid % nbx) * 128;
    const int w = tid >> 6, lane = tid & 63;
    const int wr = w >> 1, wc = w & 1;
    const int lr = lane & 15, lg = lane >> 4;

    f4_t acc[2][4] = {};

    const int r1 = tid >> 2, q1 = tid & 3;
    const unsigned short* pA1 = A + (size_t)(m0 + r1) * ldk + q1 * 8;
    const unsigned short* pB1 = Bt + (size_t)(n0 + r1) * ldk + q1 * 8;
    const unsigned short* pB2 = pB1 + (size_t)64 * ldk;
    const int wofs = w * 512;

#define STAGE(AS, BS, kk) do {                 \
        gll16(pA1 + (kk), (AS) + wofs);        \
        gll16(pB1 + (kk), (BS) + wofs);        \
        gll16(pB2 + (kk), (BS) + 2048 + wofs); } while (0)

#define COMPUTE(AS, BS) do {                                                     \
        bf8_t af[2], bfr[4];                                                     \
        _Pragma("unroll")                                                        \
        for (int f = 0; f < 2; f++)                                              \
            af[f] = *(const bf8_t*)&(AS)[(wr * 32 + f * 16 + lr) * 32 + lg * 8]; \
        _Pragma("unroll")                                                        \
        for (int f = 0; f < 4; f++)                                              \
            bfr[f] = *(const bf8_t*)&(BS)[(wc * 64 + f * 16 + lr) * 32 + lg * 8];\
        _Pragma("unroll")                                                        \
        for (int mf = 0; mf < 2; mf++)                                           \
            _Pragma("unroll")                                                    \
            for (int nf = 0; nf < 4; nf++)                                       \
                acc[mf][nf] = __builtin_amdgcn_mfma_f32_16x16x32_bf16(           \
                    af[mf], bfr[nf], acc[mf][nf], 0, 0, 0); } while (0)

    STAGE(As0, Bs0, 0);
    for (int k0 = 0; k0 + 64 < K; k0 += 64) {
        STAGE(As1, Bs1, k0 + 32);
        VMW(3); BAR();
        COMPUTE(As0, Bs0);
        BAR();
        STAGE(As0, Bs0, k0 + 64);
        VMW(3); BAR();
        COMPUTE(As1, Bs1);
        BAR();
    }
    STAGE(As1, Bs1, K - 32);
    VMW(3); BAR();
    COMPUTE(As0, Bs0);
    VMW(0); BAR();
    COMPUTE(As1, Bs1);
#undef STAGE
#undef COMPUTE

#pragma unroll
    for (int mf = 0; mf < 2; mf++) {
#pragma unroll
        for (int nf = 0; nf < 4; nf++) {
            const int n = n0 + wc * 64 + nf * 16 + lr;
            const float bv = bias[n];
#pragma unroll
            for (int j = 0; j < 4; j++) {
                const int m = m0 + wr * 32 + mf * 16 + lg * 4 + j;
                float val = acc[mf][nf][j] + bv;
                if (RESID) val += resid[(size_t)m * N + n];
                if (RELU) val = fmaxf(val, 0.f);
                if (BF16OUT) ((unsigned short*)Cout)[(size_t)m * N + n] = f2b(val);
                else         ((float*)Cout)[(size_t)m * N + n] = val;
            }
        }
    }
}

// ---------------- FFN2 split-K combine: out = x2 + b2 + p0 + p1 ----------------
__global__ __launch_bounds__(256) void k_comb(const unsigned short* __restrict__ p,
                                              const float* __restrict__ x2,
                                              const float* __restrict__ b2,
                                              float* __restrict__ out) {
    const size_t idx = ((size_t)blockIdx.x * 256 + threadIdx.x) * 8;
    us8_t a = *(const us8_t*)(p + idx);
    us8_t b = *(const us8_t*)(p + (size_t)M_ * D_ + idx);
    const int n = (int)(idx & (D_ - 1));
    f4_t x0 = *(const f4_t*)(x2 + idx), x1 = *(const f4_t*)(x2 + idx + 4);
    f4_t b0 = *(const f4_t*)(b2 + n),  b1 = *(const f4_t*)(b2 + n + 4);
    f4_t o0, o1;
#pragma unroll
    for (int c = 0; c < 4; c++) {
        o0[c] = x0[c] + b0[c] + b2f(a[c]) + b2f(b[c]);
        o1[c] = x1[c] + b1[c] + b2f(a[4 + c]) + b2f(b[4 + c]);
    }
    *(f4_t*)(out + idx) = o0;
    *(f4_t*)(out + idx + 4) = o1;
}

// ---------------- V chunk column sums: sums[bh][c][d] = colsum of chunk c ----------------
__global__ __launch_bounds__(256) void k_vchunksum(const unsigned short* __restrict__ V,
                                                   float* __restrict__ sums) {
    const int blk = blockIdx.x;          // bh*32 + c
    const int bh = blk >> 5, c = blk & 31;
    const int b = bh >> 4, h = bh & 15;
    const int d = threadIdx.x & 63, r4 = threadIdx.x >> 6;
    const unsigned short* base = V + ((size_t)(b * S_ + c * 64 + r4 * 16)) * QKV_STR + h * HD_ + d;
    float s = 0.f;
#pragma unroll
    for (int r = 0; r < 16; r++) s += b2f(base[(size_t)r * QKV_STR]);
    __shared__ float red[4][64];
    red[r4][d] = s;
    __syncthreads();
    if (r4 == 0) sums[(size_t)blk * 64 + d] = red[0][d] + red[1][d] + red[2][d] + red[3][d];
}

// ---------------- exclusive scan of chunk sums -> pre[bh][33][64] ----------------
__global__ __launch_bounds__(64) void k_vscan(const float* __restrict__ sums,
                                              float* __restrict__ pre) {
    const int bh = blockIdx.x, d = threadIdx.x;
    float cum = 0.f;
    for (int c = 0; c < 32; c++) {
        pre[((size_t)bh * 33 + c) * 64 + d] = cum;
        cum += sums[((size_t)bh * 32 + c) * 64 + d];
    }
    pre[((size_t)bh * 33 + 32) * 64 + d] = cum;
}

// ---------------- MFMA flash attention: complementary q-tile pairs, uniform block work ----------------
// V staged as adjacent-row pairs -> packed b32 LDS writes (same layout, half the write issues).
#define KS_STRIDE 72   // K tile pad: 64+8

__global__ __launch_bounds__(256) void k_attn_mfma(const unsigned short* __restrict__ QKV,
                                                   const float* __restrict__ vpre,
                                                   unsigned short* __restrict__ Out) {
    __shared__ __align__(16) unsigned short Ks[2][64 * KS_STRIDE];     // [k][d] padded
    __shared__ __align__(16) unsigned short Vt[2][64 * 64];            // [d][kv] chunk-swizzled
    __shared__ __align__(16) unsigned short Ps[4][2][16 * KS_STRIDE];  // per-wave, per-subtile [q][k]

    const int id = blockIdx.x;                   // 512 blocks
    const int wg = (id & 7) * 64 + (id >> 3);    // XCD-chunked bijective swizzle (512%8==0)
    const int qA = wg & 15;                      // tile A chunk index (0..15)
    const int qB = 31 - qA;                      // tile B chunk index (16..31)
    const int bh = wg >> 4;
    const int b = bh >> 4, h = bh & 15;
    const int tid = threadIdx.x;
    const int wq = tid >> 6;
    const int lane = tid & 63;
    const int lr = lane & 15, lg = lane >> 4;

    const unsigned short* Qp = QKV;
    const unsigned short* Kp = QKV + 1024;
    const unsigned short* Vp = QKV + 2048;

    const int kcdt[2] = {qA, qB};
    const int lastV = qB;
    const int qb = wq * 16 + lr;
    const int q0t[2] = {qA * 64, qB * 64};

    // Q fragments per subtile (B-operand: q = lr), pre-scaled by (1/8)*log2(e)
    bf8_t qfrag[2][2];
#pragma unroll
    for (int t = 0; t < 2; t++) {
        const float qs = 0.125f * 1.44269504f;
        const size_t qbase = ((size_t)(b * S_ + q0t[t] + wq * 16 + lr)) * QKV_STR + h * HD_;
#pragma unroll
        for (int ks = 0; ks < 2; ks++) {
            us8_t raw = *(const us8_t*)(Qp + qbase + ks * 32 + lg * 8);
            ui4_t p;
#pragma unroll
            for (int e = 0; e < 4; e++)
                p[e] = cvt_pk_bf16(b2f(raw[e * 2]) * qs, b2f(raw[e * 2 + 1]) * qs);
            union { ui4_t u; bf8_t b; } c; c.u = p;
            qfrag[t][ks] = c.b;
        }
    }

    // staging geometry: K rows (row0, row0+32); V rows (2*rv, 2*rv+1) packed b32
    const int row0 = tid >> 3, g = tid & 7;
    const int row1 = row0 + 32;
    const int rv = tid >> 3;                     // 0..31 row-pair index
    const unsigned short* pK0 = Kp + ((size_t)(b * S_ + row0)) * QKV_STR + h * HD_ + g * 8;
    const unsigned short* pK1 = Kp + ((size_t)(b * S_ + row1)) * QKV_STR + h * HD_ + g * 8;
    const unsigned short* pV0 = Vp + ((size_t)(b * S_ + 2 * rv)) * QKV_STR + h * HD_ + g * 8;
    const unsigned short* pV1 = pV0 + QKV_STR;   // row 2*rv+1
    const int vw = (((rv >> 2) ^ g) << 3) + (rv & 3) * 2;   // slot + within-slot offset (even)

    float l_run[2] = {0.f, 0.f};
    f4_t acc_o[2][4] = {};
    f4_t acc_pre[2][4] = {};

    // prologue
    ui4_t ck0 = *(const ui4_t*)pK0;
    ui4_t ck1 = *(const ui4_t*)pK1;
    ui4_t cv0 = *(const ui4_t*)pV0;
    ui4_t cv1 = *(const ui4_t*)pV1;
    *(ui4_t*)&Ks[0][row0 * KS_STRIDE + g * 8] = ck0;
    *(ui4_t*)&Ks[0][row1 * KS_STRIDE + g * 8] = ck1;
    {
        const unsigned short* v0 = (const unsigned short*)&cv0;
        const unsigned short* v1 = (const unsigned short*)&cv1;
#pragma unroll
        for (int e = 0; e < 8; e++) {
            const int d = g * 8 + e;
            *(unsigned*)&Vt[0][d * 64 + vw] = (unsigned)v0[e] | ((unsigned)v1[e] << 16);
        }
    }
    {
        const size_t koff = (size_t)64 * QKV_STR;
        ck0 = *(const ui4_t*)(pK0 + koff);
        ck1 = *(const ui4_t*)(pK1 + koff);
        cv0 = *(const ui4_t*)(pV0 + koff);
        cv1 = *(const ui4_t*)(pV1 + koff);
    }
    __syncthreads();

#define VSLOT(dd, ks) ((((ks) * 4 + lg) ^ (((dd) * 2 + (lr >> 3)) & 7)) << 3)

    for (int kc = 0; kc < 32; kc++) {
        const int cur = kc & 1;
        const unsigned short* Kc = Ks[cur];
        const unsigned short* Vc = Vt[cur];

        // S^T = K·Q^T for both subtiles; K frag read once, used twice
        f4_t s4[2][4] = {};
        __builtin_amdgcn_s_setprio(1);
#pragma unroll
        for (int ks = 0; ks < 2; ks++) {
#pragma unroll
            for (int kk = 0; kk < 4; kk++) {
                bf8_t kfr = *(const bf8_t*)&Kc[(kk * 16 + lr) * KS_STRIDE + ks * 32 + lg * 8];
                s4[0][kk] = __builtin_amdgcn_mfma_f32_16x16x32_bf16(kfr, qfrag[0][ks], s4[0][kk], 0, 0, 0);
                s4[1][kk] = __builtin_amdgcn_mfma_f32_16x16x32_bf16(kfr, qfrag[1][ks], s4[1][kk], 0, 0, 0);
            }
        }
        __builtin_amdgcn_s_setprio(0);

        // stage next chunk (overlaps compute)
        if (kc < 31) {
            unsigned short* Kn = Ks[cur ^ 1];
            *(ui4_t*)&Kn[row0 * KS_STRIDE + g * 8] = ck0;
            *(ui4_t*)&Kn[row1 * KS_STRIDE + g * 8] = ck1;
            if (kc + 1 <= lastV) {
                unsigned short* Vn = Vt[cur ^ 1];
                const unsigned short* v0 = (const unsigned short*)&cv0;
                const unsigned short* v1 = (const unsigned short*)&cv1;
#pragma unroll
                for (int e = 0; e < 8; e++) {
                    const int d = g * 8 + e;
                    *(unsigned*)&Vn[d * 64 + vw] = (unsigned)v0[e] | ((unsigned)v1[e] << 16);
                }
            }
        }
        if (kc < 30) {
            const size_t koff = (size_t)(kc + 2) * 64 * QKV_STR;
            ck0 = *(const ui4_t*)(pK0 + koff);
            ck1 = *(const ui4_t*)(pK1 + koff);
            if (kc + 2 <= lastV) {
                cv0 = *(const ui4_t*)(pV0 + koff);
                cv1 = *(const ui4_t*)(pV1 + koff);
            }
        }

        // fixed-max softmax: p = exp2(s), l += sum(p)
#pragma unroll
        for (int t = 0; t < 2; t++) {
            float cs = 0.f;
#pragma unroll
            for (int kk = 0; kk < 4; kk++)
#pragma unroll
                for (int j = 0; j < 4; j++) {
                    const float p = __builtin_amdgcn_exp2f(s4[t][kk][j]);
                    s4[t][kk][j] = p;
                    cs += p;
                }
            cs += __shfl_xor(cs, 16);
            cs += __shfl_xor(cs, 32);
            l_run[t] += cs;
        }

        if (kc <= qB) {
            const bool doA = (kc <= qA);
#pragma unroll
            for (int kk = 0; kk < 4; kk++) {
                const int kb = kk * 16 + lg * 4;
                ui2_t wd;
                if (kc == qB) {
                    wd[0] = cvt_pk_bf16(kb + 0 <= qb ? s4[1][kk][0] : 0.f,
                                        kb + 1 <= qb ? s4[1][kk][1] : 0.f);
                    wd[1] = cvt_pk_bf16(kb + 2 <= qb ? s4[1][kk][2] : 0.f,
                                        kb + 3 <= qb ? s4[1][kk][3] : 0.f);
                } else {
                    wd[0] = cvt_pk_bf16(s4[1][kk][0], s4[1][kk][1]);
                    wd[1] = cvt_pk_bf16(s4[1][kk][2], s4[1][kk][3]);
                }
                *(ui2_t*)&Ps[wq][1][lr * KS_STRIDE + kk * 16 + lg * 4] = wd;
            }
            if (doA) {
#pragma unroll
                for (int kk = 0; kk < 4; kk++) {
                    const int kb = kk * 16 + lg * 4;
                    ui2_t wd;
                    if (kc == qA) {
                        wd[0] = cvt_pk_bf16(kb + 0 <= qb ? s4[0][kk][0] : 0.f,
                                            kb + 1 <= qb ? s4[0][kk][1] : 0.f);
                        wd[1] = cvt_pk_bf16(kb + 2 <= qb ? s4[0][kk][2] : 0.f,
                                            kb + 3 <= qb ? s4[0][kk][3] : 0.f);
                    } else {
                        wd[0] = cvt_pk_bf16(s4[0][kk][0], s4[0][kk][1]);
                        wd[1] = cvt_pk_bf16(s4[0][kk][2], s4[0][kk][3]);
                    }
                    *(ui2_t*)&Ps[wq][0][lr * KS_STRIDE + kk * 16 + lg * 4] = wd;
                }
            }
            __builtin_amdgcn_s_setprio(1);
#pragma unroll
            for (int ks = 0; ks < 2; ks++) {
                bf8_t pf1 = *(const bf8_t*)&Ps[wq][1][lr * KS_STRIDE + ks * 32 + lg * 8];
                bf8_t pf0;
                if (doA) pf0 = *(const bf8_t*)&Ps[wq][0][lr * KS_STRIDE + ks * 32 + lg * 8];
#pragma unroll
                for (int dd = 0; dd < 4; dd++) {
                    bf8_t vf = *(const bf8_t*)&Vc[(dd * 16 + lr) * 64 + VSLOT(dd, ks)];
                    acc_o[1][dd] = __builtin_amdgcn_mfma_f32_16x16x32_bf16(vf, pf1, acc_o[1][dd], 0, 0, 0);
                    if (doA)
                        acc_o[0][dd] = __builtin_amdgcn_mfma_f32_16x16x32_bf16(vf, pf0, acc_o[0][dd], 0, 0, 0);
                }
            }
            __builtin_amdgcn_s_setprio(0);

            // diagonal partial prefix (subtile-specific kc)
#pragma unroll
            for (int t = 0; t < 2; t++) {
                if (kc == kcdt[t]) {
                    unsigned short* Pw = Ps[wq][t];
#pragma unroll
                    for (int kk = 0; kk < 4; kk++) {
                        const int kb = kk * 16 + lg * 4;
                        ui2_t wd;
                        wd[0] = (kb + 0 <= qb ? 0x3f80u : 0u) | ((kb + 1 <= qb ? 0x3f80u : 0u) << 16);
                        wd[1] = (kb + 2 <= qb ? 0x3f80u : 0u) | ((kb + 3 <= qb ? 0x3f80u : 0u) << 16);
                        *(ui2_t*)&Pw[lr * KS_STRIDE + kk * 16 + lg * 4] = wd;
                    }
#pragma unroll
                    for (int ks = 0; ks < 2; ks++) {
                        bf8_t pf = *(const bf8_t*)&Pw[lr * KS_STRIDE + ks * 32 + lg * 8];
#pragma unroll
                        for (int dd = 0; dd < 4; dd++) {
                            bf8_t vf = *(const bf8_t*)&Vc[(dd * 16 + lr) * 64 + VSLOT(dd, ks)];
                            acc_pre[t][dd] = __builtin_amdgcn_mfma_f32_16x16x32_bf16(vf, pf, acc_pre[t][dd], 0, 0, 0);
                        }
                    }
                }
            }
        }
        __syncthreads();
    }
#undef VSLOT

    // out = O/l - 1e9 * (total - chunkprefix[kcd_t] - diag_prefix)
    const float* Ct = vpre + ((size_t)bh * 33 + 32) * 64;
#pragma unroll
    for (int t = 0; t < 2; t++) {
        const float* Cq = vpre + ((size_t)bh * 33 + kcdt[t]) * 64;
        const float inv_l = 1.f / l_run[t];
        const size_t obase = ((size_t)(b * S_ + q0t[t] + wq * 16 + lr)) * D_ + h * HD_;
#pragma unroll
        for (int dd = 0; dd < 4; dd++) {
            const f4_t tq4 = *(const f4_t*)&Cq[dd * 16 + lg * 4];
            const f4_t tt4 = *(const f4_t*)&Ct[dd * 16 + lg * 4];
            float v[4];
#pragma unroll
            for (int j = 0; j < 4; j++)
                v[j] = acc_o[t][dd][j] * inv_l - 1e9f * (tt4[j] - tq4[j] - acc_pre[t][dd][j]);
            ui2_t wd;
            wd[0] = cvt_pk_bf16(v[0], v[1]);
            wd[1] = cvt_pk_bf16(v[2], v[3]);
            *(ui2_t*)&Out[obase + dd * 16 + lg * 4] = wd;
        }
    }
}

// ---------------- launch ----------------
extern "C" void kernel_launch(void* const* d_in, const int* in_sizes, int n_in,
                              void* d_out, int out_size, void* d_ws, size_t ws_size,
                              hipStream_t stream) {
    const float* x     = (const float*)d_in[0];
    const float* Wq    = (const float*)d_in[1];  const float* bq = (const float*)d_in[2];
    const float* Wk    = (const float*)d_in[3];  const float* bk = (const float*)d_in[4];
    const float* Wv    = (const float*)d_in[5];  const float* bv = (const float*)d_in[6];
    const float* Wo    = (const float*)d_in[7];  const float* bo = (const float*)d_in[8];
    const float* W1    = (const float*)d_in[9];  const float* b1 = (const float*)d_in[10];
    const float* W2    = (const float*)d_in[11]; const float* b2 = (const float*)d_in[12];
    const float* gpre  = (const float*)d_in[13]; const float* bepre  = (const float*)d_in[14];
    const float* gpost = (const float*)d_in[15]; const float* bepost = (const float*)d_in[16];

    char* ws = (char*)d_ws;
    const size_t MB = 1024 * 1024;
    unsigned short* psplit = (unsigned short*)(ws + 0 * MB);   // 16MB, FFN2 partials (over dead weights)
    unsigned short* WqkvT = (unsigned short*)(ws + 0 * MB);    // 6MB   (dead after QKV gemm)
    unsigned short* WoT   = (unsigned short*)(ws + 6 * MB);    // 2MB   (dead after O-proj)
    unsigned short* W1T   = (unsigned short*)(ws + 8 * MB);    // 8MB   (dead after FFN1)
    unsigned short* W2T   = (unsigned short*)(ws + 16 * MB);   // 8MB   (live until FFN2)
    unsigned short* xn    = (unsigned short*)(ws + 24 * MB);   // 8MB   (dead after QKV gemm)
    unsigned short* x2n   = (unsigned short*)(ws + 24 * MB);   // 8MB   (over xn)
    unsigned short* QKV   = (unsigned short*)(ws + 32 * MB);   // 24MB  (dead after attn)
    unsigned short* h1    = (unsigned short*)(ws + 32 * MB);   // 32MB  (over QKV+att)
    unsigned short* att   = (unsigned short*)(ws + 56 * MB);   // 8MB   (dead after O-proj)
    float*          x2    = (float*)(ws + 64 * MB);            // 16MB  (live to end)
    float*          bqkv  = (float*)(ws + 80 * MB);            // 12KB
    float*          vpre  = (float*)(ws + 80 * MB + 16384);    // 270KB
    float*          tab   = (float*)(ws + 80 * MB + 512 * 1024);  // 512KB rope table
    float*          vsum  = (float*)(ws + 81 * MB);            // 256KB

    k_prep<<<12308, 256, 0, stream>>>(Wq, Wk, Wv, Wo, W1, W2, bq, bk, bv,
                                      WqkvT, WoT, W1T, W2T, bqkv, tab);

    k_layernorm<<<M_, 256, 0, stream>>>(x, gpre, bepre, xn);

    // fused QKV projection + bias + RoPE (grid 768, nbx=24)
    k_gemm_bt<0, 1, 0, 1, 0><<<768, 256, 0, stream>>>(xn, WqkvT, bqkv, nullptr, QKV, tab,
                                                      M_, QKV_STR, D_, D_, 24);

    k_vchunksum<<<1024, 256, 0, stream>>>(QKV + 2048, vsum);
    k_vscan<<<32, 64, 0, stream>>>(vsum, vpre);

    k_attn_mfma<<<512, 256, 0, stream>>>(QKV, vpre, att);

    k_gemm64<0, 0, 1><<<512, 256, 0, stream>>>(att, WoT, bo, x, x2, M_, D_, D_, D_, 8);

    k_layernorm<<<M_, 256, 0, stream>>>(x2, gpost, bepost, x2n);

    k_gemm_bt<1, 1, 0, 0, 0><<<1024, 256, 0, stream>>>(x2n, W1T, b1, nullptr, h1, nullptr,
                                                       M_, DFF_, D_, D_, 32);

    // FFN2 split-K=2: grid 512, halves write bf16 partials
    k_gemm_bt<0, 1, 0, 0, 1><<<512, 256, 0, stream>>>(h1, W2T, nullptr, nullptr, psplit, nullptr,
                                                      M_, D_, 2048, DFF_, 8);
    k_comb<<<2048, 256, 0, stream>>>(psplit, x2, b2, (float*)d_out);
}

// Round 18
// 238.849 us; speedup vs baseline: 1.0473x; 1.0212x over previous
//
#include <hip/hip_runtime.h>
#include <stdint.h>

#define B_ 2
#define S_ 2048
#define D_ 1024
#define H_ 16
#define HD_ 64
#define DFF_ 4096
#define M_ 4096        // B*S
#define QKV_STR 3072   // fused QKV row stride

typedef float           f4_t  __attribute__((ext_vector_type(4)));
typedef unsigned int    ui4_t __attribute__((ext_vector_type(4)));
typedef unsigned int    ui2_t __attribute__((ext_vector_type(2)));
typedef unsigned short  us4_t __attribute__((ext_vector_type(4)));
typedef unsigned short  us8_t __attribute__((ext_vector_type(8)));
typedef __bf16          bf8_t __attribute__((ext_vector_type(8)));

__device__ __forceinline__ float b2f(unsigned short u) {
    union { unsigned int u; float f; } v; v.u = ((unsigned int)u) << 16; return v.f;
}
__device__ __forceinline__ unsigned short f2b(float f) {
    union { float f; unsigned int u; } v; v.f = f;
    unsigned int u = v.u + 0x7fffu + ((v.u >> 16) & 1u);
    return (unsigned short)(u >> 16);
}
__device__ __forceinline__ unsigned cvt_pk_bf16(float lo, float hi) {
    unsigned r;
    asm("v_cvt_pk_bf16_f32 %0, %1, %2" : "=v"(r) : "v"(lo), "v"(hi));
    return r;
}
__device__ __forceinline__ void gll16(const unsigned short* g, unsigned short* l) {
    __builtin_amdgcn_global_load_lds((const __attribute__((address_space(1))) unsigned int*)g,
                                     (__attribute__((address_space(3))) unsigned int*)l,
                                     16, 0, 0);
}

// ---------------- fused prep: 6 weight transposes + bias concat + rope table + pre-LN ----------------
__global__ __launch_bounds__(256) void k_prep(const float* __restrict__ Wq, const float* __restrict__ Wk,
                                              const float* __restrict__ Wv, const float* __restrict__ Wo,
                                              const float* __restrict__ W1, const float* __restrict__ W2,
                                              const float* __restrict__ bq, const float* __restrict__ bk,
                                              const float* __restrict__ bv,
                                              const float* __restrict__ x,  const float* __restrict__ gpre,
                                              const float* __restrict__ bepre,
                                              unsigned short* __restrict__ WqkvT, unsigned short* __restrict__ WoT,
                                              unsigned short* __restrict__ W1T, unsigned short* __restrict__ W2T,
                                              float* __restrict__ bqkv, float* __restrict__ tab,
                                              unsigned short* __restrict__ xn) {
    const int j = blockIdx.x;
    if (j < 12288) {
        const float* src; unsigned short* dst; int R, C, jj;
        if (j < 3072)      { const int r = j >> 10; src = r == 0 ? Wq : (r == 1 ? Wk : Wv);
                             dst = WqkvT + (size_t)r * 1024 * 1024; R = 1024; C = 1024; jj = j & 1023; }
        else if (j < 4096) { src = Wo; dst = WoT; R = 1024; C = 1024; jj = j - 3072; }
        else if (j < 8192) { src = W1; dst = W1T; R = 1024; C = 4096; jj = j - 4096; }
        else               { src = W2; dst = W2T; R = 4096; C = 1024; jj = j - 8192; }
        const int ntx = C >> 5;
        const int bc = (jj % ntx) * 32, br = (jj / ntx) * 32;
        __shared__ float tile[32][33];
        const int tx = threadIdx.x & 31, ty = threadIdx.x >> 5;
#pragma unroll
        for (int i = ty; i < 32; i += 8)
            tile[i][tx] = src[(size_t)(br + i) * C + bc + tx];
        __syncthreads();
#pragma unroll
        for (int i = ty; i < 32; i += 8)
            dst[(size_t)(bc + i) * R + br + tx] = f2b(tile[tx][i]);
    } else if (j < 12300) {
        const int t = (j - 12288) * 256 + threadIdx.x;
        if (t < 1024) bqkv[t] = bq[t];
        else if (t < 2048) bqkv[t] = bk[t - 1024];
        else if (t < 3072) bqkv[t] = bv[t - 2048];
    } else if (j < 12308) {
        const int base = (j - 12300) * 256 + threadIdx.x;
#pragma unroll
        for (int e = 0; e < 32; e++) {
            const int idx = base + e * 2048;
            const int s = idx >> 5, i = idx & 31;
            const float freq = exp2f(-(float)i * 0.4152410118609203f);
            float sn, cs;
            sincosf((float)s * freq, &sn, &cs);
            tab[s * 64 + i] = cs;
            tab[s * 64 + 32 + i] = sn;
        }
    } else {
        // pre-attention layernorm, row = j - 12308
        const int row = j - 12308;
        const int t = threadIdx.x;
        const float* xr = x + (size_t)row * D_;
        f4_t v = *(const f4_t*)&xr[t * 4];
        float s = v[0] + v[1] + v[2] + v[3];
#pragma unroll
        for (int o = 32; o >= 1; o >>= 1) s += __shfl_down(s, o);
        __shared__ float red[4];
        const int w = t >> 6, lane = t & 63;
        if (lane == 0) red[w] = s;
        __syncthreads();
        const float mean = (red[0] + red[1] + red[2] + red[3]) * (1.f / D_);
        f4_t d;
#pragma unroll
        for (int c = 0; c < 4; c++) d[c] = v[c] - mean;
        float ss = d[0]*d[0] + d[1]*d[1] + d[2]*d[2] + d[3]*d[3];
#pragma unroll
        for (int o = 32; o >= 1; o >>= 1) ss += __shfl_down(ss, o);
        __syncthreads();
        if (lane == 0) red[w] = ss;
        __syncthreads();
        const float var = (red[0] + red[1] + red[2] + red[3]) * (1.f / D_);
        const float rstd = rsqrtf(var + 1e-5f);
        f4_t gv = *(const f4_t*)&gpre[t * 4];
        f4_t bv = *(const f4_t*)&bepre[t * 4];
        us4_t o4;
#pragma unroll
        for (int c = 0; c < 4; c++) o4[c] = f2b(d[c] * rstd * gv[c] + bv[c]);
        *(us4_t*)&xn[(size_t)row * D_ + t * 4] = o4;
    }
}

// ---------------- layernorm fp32 row(1024) -> bf16 ----------------
__global__ __launch_bounds__(256) void k_layernorm(const float* __restrict__ x,
                                                   const float* __restrict__ g,
                                                   const float* __restrict__ be,
                                                   unsigned short* __restrict__ out) {
    const int row = blockIdx.x;
    const int t = threadIdx.x;
    const float* xr = x + (size_t)row * D_;
    f4_t v = *(const f4_t*)&xr[t * 4];
    float s = v[0] + v[1] + v[2] + v[3];
#pragma unroll
    for (int o = 32; o >= 1; o >>= 1) s += __shfl_down(s, o);
    __shared__ float red[4];
    const int w = t >> 6, lane = t & 63;
    if (lane == 0) red[w] = s;
    __syncthreads();
    const float mean = (red[0] + red[1] + red[2] + red[3]) * (1.f / D_);
    f4_t d;
#pragma unroll
    for (int c = 0; c < 4; c++) d[c] = v[c] - mean;
    float ss = d[0]*d[0] + d[1]*d[1] + d[2]*d[2] + d[3]*d[3];
#pragma unroll
    for (int o = 32; o >= 1; o >>= 1) ss += __shfl_down(ss, o);
    __syncthreads();
    if (lane == 0) red[w] = ss;
    __syncthreads();
    const float var = (red[0] + red[1] + red[2] + red[3]) * (1.f / D_);
    const float rstd = rsqrtf(var + 1e-5f);
    f4_t gv = *(const f4_t*)&g[t * 4];
    f4_t bv = *(const f4_t*)&be[t * 4];
    us4_t o4;
#pragma unroll
    for (int c = 0; c < 4; c++) o4[c] = f2b(d[c] * rstd * gv[c] + bv[c]);
    *(us4_t*)&out[(size_t)row * D_ + t * 4] = o4;
}

#define VMW(n) asm volatile("s_waitcnt vmcnt(" #n ")" ::: "memory")
#define BAR()  __builtin_amdgcn_s_barrier()

// ---------------- bf16 MFMA GEMM 128x128, BK=32, counted-vmcnt dbuf, XCD-chunked 1D grid ----------------
template<int RELU, int BF16OUT, int RESID, int ROPE, int SPLIT>
__global__ __launch_bounds__(256) void k_gemm_bt(const unsigned short* __restrict__ A,
                                                 const unsigned short* __restrict__ Bt,
                                                 const float* __restrict__ bias,
                                                 const float* __restrict__ resid,
                                                 void* __restrict__ Cout,
                                                 const float* __restrict__ tab,
                                                 int M, int N, int K, int ldk, int nbx) {
    __shared__ __align__(16) unsigned short As0[128 * 32];
    __shared__ __align__(16) unsigned short Bs0[128 * 32];
    __shared__ __align__(16) unsigned short As1[128 * 32];
    __shared__ __align__(16) unsigned short Bs1[128 * 32];
    const int tid = threadIdx.x;
    const int cpx = gridDim.x >> 3;
    int nid = (blockIdx.x & 7) * cpx + (blockIdx.x >> 3);
    int half = 0;
    if (SPLIT) { half = nid >> 8; nid &= 255; A += 2048 * half; Bt += 2048 * half; }
    const int m0 = (nid / nbx) * 128, n0 = (nid % nbx) * 128;
    const int w = tid >> 6, lane = tid & 63;
    const int wr = w >> 1, wc = w & 1;
    const int lr = lane & 15, lg = lane >> 4;

    f4_t acc[4][4] = {};

    const int r1 = tid >> 2, q1 = tid & 3;
    const unsigned short* pA1 = A + (size_t)(m0 + r1) * ldk + q1 * 8;
    const unsigned short* pA2 = pA1 + (size_t)64 * ldk;
    const unsigned short* pB1 = Bt + (size_t)(n0 + r1) * ldk + q1 * 8;
    const unsigned short* pB2 = pB1 + (size_t)64 * ldk;
    const int wofs = w * 512;

#define STAGE(AS, BS, kk) do {                 \
        gll16(pA1 + (kk), (AS) + wofs);        \
        gll16(pA2 + (kk), (AS) + 2048 + wofs); \
        gll16(pB1 + (kk), (BS) + wofs);        \
        gll16(pB2 + (kk), (BS) + 2048 + wofs); } while (0)

#define COMPUTE(AS, BS) do {                                                     \
        bf8_t af[4], bfr[4];                                                     \
        _Pragma("unroll")                                                        \
        for (int f = 0; f < 4; f++) {                                            \
            af[f]  = *(const bf8_t*)&(AS)[(wr * 64 + f * 16 + lr) * 32 + lg * 8];\
            bfr[f] = *(const bf8_t*)&(BS)[(wc * 64 + f * 16 + lr) * 32 + lg * 8];\
        }                                                                        \
        _Pragma("unroll")                                                        \
        for (int mf = 0; mf < 4; mf++)                                           \
            _Pragma("unroll")                                                    \
            for (int nf = 0; nf < 4; nf++)                                       \
                acc[mf][nf] = __builtin_amdgcn_mfma_f32_16x16x32_bf16(           \
                    af[mf], bfr[nf], acc[mf][nf], 0, 0, 0); } while (0)

    STAGE(As0, Bs0, 0);
    for (int k0 = 0; k0 + 64 < K; k0 += 64) {
        STAGE(As1, Bs1, k0 + 32);
        VMW(4); BAR();
        COMPUTE(As0, Bs0);
        BAR();
        STAGE(As0, Bs0, k0 + 64);
        VMW(4); BAR();
        COMPUTE(As1, Bs1);
        BAR();
    }
    STAGE(As1, Bs1, K - 32);
    VMW(4); BAR();
    COMPUTE(As0, Bs0);
    VMW(0); BAR();
    COMPUTE(As1, Bs1);
#undef STAGE
#undef COMPUTE

    if (SPLIT) {
        unsigned short* outp = (unsigned short*)Cout + (size_t)half * ((size_t)M * N);
#pragma unroll
        for (int mf = 0; mf < 4; mf++)
#pragma unroll
            for (int nf = 0; nf < 4; nf++) {
                const int n = n0 + wc * 64 + nf * 16 + lr;
#pragma unroll
                for (int j = 0; j < 4; j++) {
                    const int m = m0 + wr * 64 + mf * 16 + lg * 4 + j;
                    outp[(size_t)m * N + n] = f2b(acc[mf][nf][j]);
                }
            }
        return;
    }
    if (ROPE) {
#pragma unroll
        for (int mf = 0; mf < 4; mf++)
#pragma unroll
            for (int nf = 0; nf < 4; nf++) {
                const float bv = bias[n0 + wc * 64 + nf * 16 + lr];
#pragma unroll
                for (int j = 0; j < 4; j++) acc[mf][nf][j] += bv;
            }
        if (n0 < 2048) {
#pragma unroll
            for (int mf = 0; mf < 4; mf++)
#pragma unroll
                for (int j = 0; j < 4; j++) {
                    const int srow = (m0 + wr * 64 + mf * 16 + lg * 4 + j) & 2047;
                    const float* tr = tab + srow * 64;
#pragma unroll
                    for (int t = 0; t < 2; t++) {
                        const float cs = tr[t * 16 + lr];
                        const float sn = tr[32 + t * 16 + lr];
                        const float lo = acc[mf][t][j], hi = acc[mf][t + 2][j];
                        acc[mf][t][j]     = lo * cs - hi * sn;
                        acc[mf][t + 2][j] = hi * cs + lo * sn;
                    }
                }
        }
        unsigned short* outp = (unsigned short*)Cout;
#pragma unroll
        for (int mf = 0; mf < 4; mf++)
#pragma unroll
            for (int nf = 0; nf < 4; nf++) {
                const int n = n0 + wc * 64 + nf * 16 + lr;
#pragma unroll
                for (int j = 0; j < 4; j++) {
                    const int m = m0 + wr * 64 + mf * 16 + lg * 4 + j;
                    outp[(size_t)m * N + n] = f2b(acc[mf][nf][j]);
                }
            }
        return;
    }
#pragma unroll
    for (int mf = 0; mf < 4; mf++) {
#pragma unroll
        for (int nf = 0; nf < 4; nf++) {
            const int n = n0 + wc * 64 + nf * 16 + lr;
            const float bv = bias[n];
#pragma unroll
            for (int j = 0; j < 4; j++) {
                const int m = m0 + wr * 64 + mf * 16 + lg * 4 + j;
                float val = acc[mf][nf][j] + bv;
                if (RESID) val += resid[(size_t)m * N + n];
                if (RELU) val = fmaxf(val, 0.f);
                if (BF16OUT) ((unsigned short*)Cout)[(size_t)m * N + n] = f2b(val);
                else         ((float*)Cout)[(size_t)m * N + n] = val;
            }
        }
    }
}

// ---------------- bf16 MFMA GEMM 64x128, BK=32, counted-vmcnt dbuf ----------------
template<int RELU, int BF16OUT, int RESID>
__global__ __launch_bounds__(256) void k_gemm64(const unsigned short* __restrict__ A,
                                                const unsigned short* __restrict__ Bt,
                                                const float* __restrict__ bias,
                                                const float* __restrict__ resid,
                                                void* __restrict__ Cout,
                                                int M, int N, int K, int ldk, int nbx) {
    __shared__ __align__(16) unsigned short As0[64 * 32];
    __shared__ __align__(16) unsigned short Bs0[128 * 32];
    __shared__ __align__(16) unsigned short As1[64 * 32];
    __shared__ __align__(16) unsigned short Bs1[128 * 32];
    const int tid = threadIdx.x;
    const int cpx = gridDim.x >> 3;
    const int nid = (blockIdx.x & 7) * cpx + (blockIdx.x >> 3);
    const int m0 = (nid / nbx) * 64, n0 = (nid % nbx) * 128;
    const int w = tid >> 6, lane = tid & 63;
    const int wr = w >> 1, wc = w & 1;
    const int lr = lane & 15, lg = lane >> 4;

    f4_t acc[2][4] = {};

    const int r1 = tid >> 2, q1 = tid & 3;
    const unsigned short* pA1 = A + (size_t)(m0 + r1) * ldk + q1 * 8;
    const unsigned short* pB1 = Bt + (size_t)(n0 + r1) * ldk + q1 * 8;
    const unsigned short* pB2 = pB1 + (size_t)64 * ldk;
    const int wofs = w * 512;

#define STAGE(AS, BS, kk) do {                 \
        gll16(pA1 + (kk), (AS) + wofs);        \
        gll16(pB1 + (kk), (BS) + wofs);        \
        gll16(pB2 + (kk), (BS) + 2048 + wofs); } while (0)

#define COMPUTE(AS, BS) do {                                                     \
        bf8_t af[2], bfr[4];                                                     \
        _Pragma("unroll")                                                        \
        for (int f = 0; f < 2; f++)                                              \
            af[f] = *(const bf8_t*)&(AS)[(wr * 32 + f * 16 + lr) * 32 + lg * 8]; \
        _Pragma("unroll")                                                        \
        for (int f = 0; f < 4; f++)                                              \
            bfr[f] = *(const bf8_t*)&(BS)[(wc * 64 + f * 16 + lr) * 32 + lg * 8];\
        _Pragma("unroll")                                                        \
        for (int mf = 0; mf < 2; mf++)                                           \
            _Pragma("unroll")                                                    \
            for (int nf = 0; nf < 4; nf++)                                       \
                acc[mf][nf] = __builtin_amdgcn_mfma_f32_16x16x32_bf16(           \
                    af[mf], bfr[nf], acc[mf][nf], 0, 0, 0); } while (0)

    STAGE(As0, Bs0, 0);
    for (int k0 = 0; k0 + 64 < K; k0 += 64) {
        STAGE(As1, Bs1, k0 + 32);
        VMW(3); BAR();
        COMPUTE(As0, Bs0);
        BAR();
        STAGE(As0, Bs0, k0 + 64);
        VMW(3); BAR();
        COMPUTE(As1, Bs1);
        BAR();
    }
    STAGE(As1, Bs1, K - 32);
    VMW(3); BAR();
    COMPUTE(As0, Bs0);
    VMW(0); BAR();
    COMPUTE(As1, Bs1);
#undef STAGE
#undef COMPUTE

#pragma unroll
    for (int mf = 0; mf < 2; mf++) {
#pragma unroll
        for (int nf = 0; nf < 4; nf++) {
            const int n = n0 + wc * 64 + nf * 16 + lr;
            const float bv = bias[n];
#pragma unroll
            for (int j = 0; j < 4; j++) {
                const int m = m0 + wr * 32 + mf * 16 + lg * 4 + j;
                float val = acc[mf][nf][j] + bv;
                if (RESID) val += resid[(size_t)m * N + n];
                if (RELU) val = fmaxf(val, 0.f);
                if (BF16OUT) ((unsigned short*)Cout)[(size_t)m * N + n] = f2b(val);
                else         ((float*)Cout)[(size_t)m * N + n] = val;
            }
        }
    }
}

// ---------------- FFN2 split-K combine: out = x2 + b2 + p0 + p1 ----------------
__global__ __launch_bounds__(256) void k_comb(const unsigned short* __restrict__ p,
                                              const float* __restrict__ x2,
                                              const float* __restrict__ b2,
                                              float* __restrict__ out) {
    const size_t idx = ((size_t)blockIdx.x * 256 + threadIdx.x) * 8;
    us8_t a = *(const us8_t*)(p + idx);
    us8_t b = *(const us8_t*)(p + (size_t)M_ * D_ + idx);
    const int n = (int)(idx & (D_ - 1));
    f4_t x0 = *(const f4_t*)(x2 + idx), x1 = *(const f4_t*)(x2 + idx + 4);
    f4_t b0 = *(const f4_t*)(b2 + n),  b1 = *(const f4_t*)(b2 + n + 4);
    f4_t o0, o1;
#pragma unroll
    for (int c = 0; c < 4; c++) {
        o0[c] = x0[c] + b0[c] + b2f(a[c]) + b2f(b[c]);
        o1[c] = x1[c] + b1[c] + b2f(a[4 + c]) + b2f(b[4 + c]);
    }
    *(f4_t*)(out + idx) = o0;
    *(f4_t*)(out + idx + 4) = o1;
}

// ---------------- V chunk column sums: sums[bh][c][d] = colsum of chunk c ----------------
__global__ __launch_bounds__(256) void k_vchunksum(const unsigned short* __restrict__ V,
                                                   float* __restrict__ sums) {
    const int blk = blockIdx.x;          // bh*32 + c
    const int bh = blk >> 5, c = blk & 31;
    const int b = bh >> 4, h = bh & 15;
    const int d = threadIdx.x & 63, r4 = threadIdx.x >> 6;
    const unsigned short* base = V + ((size_t)(b * S_ + c * 64 + r4 * 16)) * QKV_STR + h * HD_ + d;
    float s = 0.f;
#pragma unroll
    for (int r = 0; r < 16; r++) s += b2f(base[(size_t)r * QKV_STR]);
    __shared__ float red[4][64];
    red[r4][d] = s;
    __syncthreads();
    if (r4 == 0) sums[(size_t)blk * 64 + d] = red[0][d] + red[1][d] + red[2][d] + red[3][d];
}

// ---------------- exclusive scan of chunk sums -> pre[bh][33][64] ----------------
__global__ __launch_bounds__(64) void k_vscan(const float* __restrict__ sums,
                                              float* __restrict__ pre) {
    const int bh = blockIdx.x, d = threadIdx.x;
    float cum = 0.f;
    for (int c = 0; c < 32; c++) {
        pre[((size_t)bh * 33 + c) * 64 + d] = cum;
        cum += sums[((size_t)bh * 32 + c) * 64 + d];
    }
    pre[((size_t)bh * 33 + 32) * 64 + d] = cum;
}

// ---------------- MFMA flash attention: complementary q-tile pairs, uniform block work ----------------
// V staged as adjacent-row pairs -> packed b32 LDS writes (same layout, half the write issues).
#define KS_STRIDE 72   // K tile pad: 64+8

__global__ __launch_bounds__(256) void k_attn_mfma(const unsigned short* __restrict__ QKV,
                                                   const float* __restrict__ vpre,
                                                   unsigned short* __restrict__ Out) {
    __shared__ __align__(16) unsigned short Ks[2][64 * KS_STRIDE];     // [k][d] padded
    __shared__ __align__(16) unsigned short Vt[2][64 * 64];            // [d][kv] chunk-swizzled
    __shared__ __align__(16) unsigned short Ps[4][2][16 * KS_STRIDE];  // per-wave, per-subtile [q][k]

    const int id = blockIdx.x;                   // 512 blocks
    const int wg = (id & 7) * 64 + (id >> 3);    // XCD-chunked bijective swizzle (512%8==0)
    const int qA = wg & 15;                      // tile A chunk index (0..15)
    const int qB = 31 - qA;                      // tile B chunk index (16..31)
    const int bh = wg >> 4;
    const int b = bh >> 4, h = bh & 15;
    const int tid = threadIdx.x;
    const int wq = tid >> 6;
    const int lane = tid & 63;
    const int lr = lane & 15, lg = lane >> 4;

    const unsigned short* Qp = QKV;
    const unsigned short* Kp = QKV + 1024;
    const unsigned short* Vp = QKV + 2048;

    const int kcdt[2] = {qA, qB};
    const int lastV = qB;
    const int qb = wq * 16 + lr;
    const int q0t[2] = {qA * 64, qB * 64};

    // Q fragments per subtile (B-operand: q = lr), pre-scaled by (1/8)*log2(e)
    bf8_t qfrag[2][2];
#pragma unroll
    for (int t = 0; t < 2; t++) {
        const float qs = 0.125f * 1.44269504f;
        const size_t qbase = ((size_t)(b * S_ + q0t[t] + wq * 16 + lr)) * QKV_STR + h * HD_;
#pragma unroll
        for (int ks = 0; ks < 2; ks++) {
            us8_t raw = *(const us8_t*)(Qp + qbase + ks * 32 + lg * 8);
            ui4_t p;
#pragma unroll
            for (int e = 0; e < 4; e++)
                p[e] = cvt_pk_bf16(b2f(raw[e * 2]) * qs, b2f(raw[e * 2 + 1]) * qs);
            union { ui4_t u; bf8_t b; } c; c.u = p;
            qfrag[t][ks] = c.b;
        }
    }

    // staging geometry: K rows (row0, row0+32); V rows (2*rv, 2*rv+1) packed b32
    const int row0 = tid >> 3, g = tid & 7;
    const int row1 = row0 + 32;
    const int rv = tid >> 3;                     // 0..31 row-pair index
    const unsigned short* pK0 = Kp + ((size_t)(b * S_ + row0)) * QKV_STR + h * HD_ + g * 8;
    const unsigned short* pK1 = Kp + ((size_t)(b * S_ + row1)) * QKV_STR + h * HD_ + g * 8;
    const unsigned short* pV0 = Vp + ((size_t)(b * S_ + 2 * rv)) * QKV_STR + h * HD_ + g * 8;
    const unsigned short* pV1 = pV0 + QKV_STR;   // row 2*rv+1
    const int vw = (((rv >> 2) ^ g) << 3) + (rv & 3) * 2;   // slot + within-slot offset (even)

    float l_run[2] = {0.f, 0.f};
    f4_t acc_o[2][4] = {};
    f4_t acc_pre[2][4] = {};

    // prologue
    ui4_t ck0 = *(const ui4_t*)pK0;
    ui4_t ck1 = *(const ui4_t*)pK1;
    ui4_t cv0 = *(const ui4_t*)pV0;
    ui4_t cv1 = *(const ui4_t*)pV1;
    *(ui4_t*)&Ks[0][row0 * KS_STRIDE + g * 8] = ck0;
    *(ui4_t*)&Ks[0][row1 * KS_STRIDE + g * 8] = ck1;
    {
        const unsigned short* v0 = (const unsigned short*)&cv0;
        const unsigned short* v1 = (const unsigned short*)&cv1;
#pragma unroll
        for (int e = 0; e < 8; e++) {
            const int d = g * 8 + e;
            *(unsigned*)&Vt[0][d * 64 + vw] = (unsigned)v0[e] | ((unsigned)v1[e] << 16);
        }
    }
    {
        const size_t koff = (size_t)64 * QKV_STR;
        ck0 = *(const ui4_t*)(pK0 + koff);
        ck1 = *(const ui4_t*)(pK1 + koff);
        cv0 = *(const ui4_t*)(pV0 + koff);
        cv1 = *(const ui4_t*)(pV1 + koff);
    }
    __syncthreads();

#define VSLOT(dd, ks) ((((ks) * 4 + lg) ^ (((dd) * 2 + (lr >> 3)) & 7)) << 3)

    for (int kc = 0; kc < 32; kc++) {
        const int cur = kc & 1;
        const unsigned short* Kc = Ks[cur];
        const unsigned short* Vc = Vt[cur];

        // S^T = K·Q^T for both subtiles; K frag read once, used twice
        f4_t s4[2][4] = {};
        __builtin_amdgcn_s_setprio(1);
#pragma unroll
        for (int ks = 0; ks < 2; ks++) {
#pragma unroll
            for (int kk = 0; kk < 4; kk++) {
                bf8_t kfr = *(const bf8_t*)&Kc[(kk * 16 + lr) * KS_STRIDE + ks * 32 + lg * 8];
                s4[0][kk] = __builtin_amdgcn_mfma_f32_16x16x32_bf16(kfr, qfrag[0][ks], s4[0][kk], 0, 0, 0);
                s4[1][kk] = __builtin_amdgcn_mfma_f32_16x16x32_bf16(kfr, qfrag[1][ks], s4[1][kk], 0, 0, 0);
            }
        }
        __builtin_amdgcn_s_setprio(0);

        // stage next chunk (overlaps compute)
        if (kc < 31) {
            unsigned short* Kn = Ks[cur ^ 1];
            *(ui4_t*)&Kn[row0 * KS_STRIDE + g * 8] = ck0;
            *(ui4_t*)&Kn[row1 * KS_STRIDE + g * 8] = ck1;
            if (kc + 1 <= lastV) {
                unsigned short* Vn = Vt[cur ^ 1];
                const unsigned short* v0 = (const unsigned short*)&cv0;
                const unsigned short* v1 = (const unsigned short*)&cv1;
#pragma unroll
                for (int e = 0; e < 8; e++) {
                    const int d = g * 8 + e;
                    *(unsigned*)&Vn[d * 64 + vw] = (unsigned)v0[e] | ((unsigned)v1[e] << 16);
                }
            }
        }
        if (kc < 30) {
            const size_t koff = (size_t)(kc + 2) * 64 * QKV_STR;
            ck0 = *(const ui4_t*)(pK0 + koff);
            ck1 = *(const ui4_t*)(pK1 + koff);
            if (kc + 2 <= lastV) {
                cv0 = *(const ui4_t*)(pV0 + koff);
                cv1 = *(const ui4_t*)(pV1 + koff);
            }
        }

        // fixed-max softmax: p = exp2(s), l += sum(p)
#pragma unroll
        for (int t = 0; t < 2; t++) {
            float cs = 0.f;
#pragma unroll
            for (int kk = 0; kk < 4; kk++)
#pragma unroll
                for (int j = 0; j < 4; j++) {
                    const float p = __builtin_amdgcn_exp2f(s4[t][kk][j]);
                    s4[t][kk][j] = p;
                    cs += p;
                }
            cs += __shfl_xor(cs, 16);
            cs += __shfl_xor(cs, 32);
            l_run[t] += cs;
        }

        if (kc <= qB) {
            const bool doA = (kc <= qA);
#pragma unroll
            for (int kk = 0; kk < 4; kk++) {
                const int kb = kk * 16 + lg * 4;
                ui2_t wd;
                if (kc == qB) {
                    wd[0] = cvt_pk_bf16(kb + 0 <= qb ? s4[1][kk][0] : 0.f,
                                        kb + 1 <= qb ? s4[1][kk][1] : 0.f);
                    wd[1] = cvt_pk_bf16(kb + 2 <= qb ? s4[1][kk][2] : 0.f,
                                        kb + 3 <= qb ? s4[1][kk][3] : 0.f);
                } else {
                    wd[0] = cvt_pk_bf16(s4[1][kk][0], s4[1][kk][1]);
                    wd[1] = cvt_pk_bf16(s4[1][kk][2], s4[1][kk][3]);
                }
                *(ui2_t*)&Ps[wq][1][lr * KS_STRIDE + kk * 16 + lg * 4] = wd;
            }
            if (doA) {
#pragma unroll
                for (int kk = 0; kk < 4; kk++) {
                    const int kb = kk * 16 + lg * 4;
                    ui2_t wd;
                    if (kc == qA) {
                        wd[0] = cvt_pk_bf16(kb + 0 <= qb ? s4[0][kk][0] : 0.f,
                                            kb + 1 <= qb ? s4[0][kk][1] : 0.f);
                        wd[1] = cvt_pk_bf16(kb + 2 <= qb ? s4[0][kk][2] : 0.f,
                                            kb + 3 <= qb ? s4[0][kk][3] : 0.f);
                    } else {
                        wd[0] = cvt_pk_bf16(s4[0][kk][0], s4[0][kk][1]);
                        wd[1] = cvt_pk_bf16(s4[0][kk][2], s4[0][kk][3]);
                    }
                    *(ui2_t*)&Ps[wq][0][lr * KS_STRIDE + kk * 16 + lg * 4] = wd;
                }
            }
            __builtin_amdgcn_s_setprio(1);
#pragma unroll
            for (int ks = 0; ks < 2; ks++) {
                bf8_t pf1 = *(const bf8_t*)&Ps[wq][1][lr * KS_STRIDE + ks * 32 + lg * 8];
                bf8_t pf0;
                if (doA) pf0 = *(const bf8_t*)&Ps[wq][0][lr * KS_STRIDE + ks * 32 + lg * 8];
#pragma unroll
                for (int dd = 0; dd < 4; dd++) {
                    bf8_t vf = *(const bf8_t*)&Vc[(dd * 16 + lr) * 64 + VSLOT(dd, ks)];
                    acc_o[1][dd] = __builtin_amdgcn_mfma_f32_16x16x32_bf16(vf, pf1, acc_o[1][dd], 0, 0, 0);
                    if (doA)
                        acc_o[0][dd] = __builtin_amdgcn_mfma_f32_16x16x32_bf16(vf, pf0, acc_o[0][dd], 0, 0, 0);
                }
            }
            __builtin_amdgcn_s_setprio(0);

            // diagonal partial prefix (subtile-specific kc)
#pragma unroll
            for (int t = 0; t < 2; t++) {
                if (kc == kcdt[t]) {
                    unsigned short* Pw = Ps[wq][t];
#pragma unroll
                    for (int kk = 0; kk < 4; kk++) {
                        const int kb = kk * 16 + lg * 4;
                        ui2_t wd;
                        wd[0] = (kb + 0 <= qb ? 0x3f80u : 0u) | ((kb + 1 <= qb ? 0x3f80u : 0u) << 16);
                        wd[1] = (kb + 2 <= qb ? 0x3f80u : 0u) | ((kb + 3 <= qb ? 0x3f80u : 0u) << 16);
                        *(ui2_t*)&Pw[lr * KS_STRIDE + kk * 16 + lg * 4] = wd;
                    }
#pragma unroll
                    for (int ks = 0; ks < 2; ks++) {
                        bf8_t pf = *(const bf8_t*)&Pw[lr * KS_STRIDE + ks * 32 + lg * 8];
#pragma unroll
                        for (int dd = 0; dd < 4; dd++) {
                            bf8_t vf = *(const bf8_t*)&Vc[(dd * 16 + lr) * 64 + VSLOT(dd, ks)];
                            acc_pre[t][dd] = __builtin_amdgcn_mfma_f32_16x16x32_bf16(vf, pf, acc_pre[t][dd], 0, 0, 0);
                        }
                    }
                }
            }
        }
        __syncthreads();
    }
#undef VSLOT

    // out = O/l - 1e9 * (total - chunkprefix[kcd_t] - diag_prefix)
    const float* Ct = vpre + ((size_t)bh * 33 + 32) * 64;
#pragma unroll
    for (int t = 0; t < 2; t++) {
        const float* Cq = vpre + ((size_t)bh * 33 + kcdt[t]) * 64;
        const float inv_l = 1.f / l_run[t];
        const size_t obase = ((size_t)(b * S_ + q0t[t] + wq * 16 + lr)) * D_ + h * HD_;
#pragma unroll
        for (int dd = 0; dd < 4; dd++) {
            const f4_t tq4 = *(const f4_t*)&Cq[dd * 16 + lg * 4];
            const f4_t tt4 = *(const f4_t*)&Ct[dd * 16 + lg * 4];
            float v[4];
#pragma unroll
            for (int j = 0; j < 4; j++)
                v[j] = acc_o[t][dd][j] * inv_l - 1e9f * (tt4[j] - tq4[j] - acc_pre[t][dd][j]);
            ui2_t wd;
            wd[0] = cvt_pk_bf16(v[0], v[1]);
            wd[1] = cvt_pk_bf16(v[2], v[3]);
            *(ui2_t*)&Out[obase + dd * 16 + lg * 4] = wd;
        }
    }
}

// ---------------- launch ----------------
extern "C" void kernel_launch(void* const* d_in, const int* in_sizes, int n_in,
                              void* d_out, int out_size, void* d_ws, size_t ws_size,
                              hipStream_t stream) {
    const float* x     = (const float*)d_in[0];
    const float* Wq    = (const float*)d_in[1];  const float* bq = (const float*)d_in[2];
    const float* Wk    = (const float*)d_in[3];  const float* bk = (const float*)d_in[4];
    const float* Wv    = (const float*)d_in[5];  const float* bv = (const float*)d_in[6];
    const float* Wo    = (const float*)d_in[7];  const float* bo = (const float*)d_in[8];
    const float* W1    = (const float*)d_in[9];  const float* b1 = (const float*)d_in[10];
    const float* W2    = (const float*)d_in[11]; const float* b2 = (const float*)d_in[12];
    const float* gpre  = (const float*)d_in[13]; const float* bepre  = (const float*)d_in[14];
    const float* gpost = (const float*)d_in[15]; const float* bepost = (const float*)d_in[16];

    char* ws = (char*)d_ws;
    const size_t MB = 1024 * 1024;
    unsigned short* psplit = (unsigned short*)(ws + 0 * MB);   // 16MB, FFN2 partials (over dead weights)
    unsigned short* WqkvT = (unsigned short*)(ws + 0 * MB);    // 6MB   (dead after QKV gemm)
    unsigned short* WoT   = (unsigned short*)(ws + 6 * MB);    // 2MB   (dead after O-proj)
    unsigned short* W1T   = (unsigned short*)(ws + 8 * MB);    // 8MB   (dead after FFN1)
    unsigned short* W2T   = (unsigned short*)(ws + 16 * MB);   // 8MB   (live until FFN2)
    unsigned short* xn    = (unsigned short*)(ws + 24 * MB);   // 8MB   (dead after QKV gemm)
    unsigned short* x2n   = (unsigned short*)(ws + 24 * MB);   // 8MB   (over xn)
    unsigned short* QKV   = (unsigned short*)(ws + 32 * MB);   // 24MB  (dead after attn)
    unsigned short* h1    = (unsigned short*)(ws + 32 * MB);   // 32MB  (over QKV+att)
    unsigned short* att   = (unsigned short*)(ws + 56 * MB);   // 8MB   (dead after O-proj)
    float*          x2    = (float*)(ws + 64 * MB);            // 16MB  (live to end)
    float*          bqkv  = (float*)(ws + 80 * MB);            // 12KB
    float*          vpre  = (float*)(ws + 80 * MB + 16384);    // 270KB
    float*          tab   = (float*)(ws + 80 * MB + 512 * 1024);  // 512KB rope table
    float*          vsum  = (float*)(ws + 81 * MB);            // 256KB

    // prep: transposes + bias + rope table + pre-LN (grid 12308 + 4096)
    k_prep<<<16404, 256, 0, stream>>>(Wq, Wk, Wv, Wo, W1, W2, bq, bk, bv,
                                      x, gpre, bepre,
                                      WqkvT, WoT, W1T, W2T, bqkv, tab, xn);

    // fused QKV projection + bias + RoPE (grid 768, nbx=24)
    k_gemm_bt<0, 1, 0, 1, 0><<<768, 256, 0, stream>>>(xn, WqkvT, bqkv, nullptr, QKV, tab,
                                                      M_, QKV_STR, D_, D_, 24);

    k_vchunksum<<<1024, 256, 0, stream>>>(QKV + 2048, vsum);
    k_vscan<<<32, 64, 0, stream>>>(vsum, vpre);

    k_attn_mfma<<<512, 256, 0, stream>>>(QKV, vpre, att);

    k_gemm64<0, 0, 1><<<512, 256, 0, stream>>>(att, WoT, bo, x, x2, M_, D_, D_, D_, 8);

    k_layernorm<<<M_, 256, 0, stream>>>(x2, gpost, bepost, x2n);

    k_gemm_bt<1, 1, 0, 0, 0><<<1024, 256, 0, stream>>>(x2n, W1T, b1, nullptr, h1, nullptr,
                                                       M_, DFF_, D_, D_, 32);

    // FFN2 split-K=2: grid 512, halves write bf16 partials
    k_gemm_bt<0, 1, 0, 0, 1><<<512, 256, 0, stream>>>(h1, W2T, nullptr, nullptr, psplit, nullptr,
                                                      M_, D_, 2048, DFF_, 8);
    k_comb<<<2048, 256, 0, stream>>>(psplit, x2, b2, (float*)d_out);
}

// Round 19
// 235.418 us; speedup vs baseline: 1.0625x; 1.0146x over previous
//
#include <hip/hip_runtime.h>
#include <stdint.h>

#define B_ 2
#define S_ 2048
#define D_ 1024
#define H_ 16
#define HD_ 64
#define DFF_ 4096
#define M_ 4096        // B*S
#define QKV_STR 3072   // fused QKV row stride

typedef float           f4_t  __attribute__((ext_vector_type(4)));
typedef unsigned int    ui4_t __attribute__((ext_vector_type(4)));
typedef unsigned int    ui2_t __attribute__((ext_vector_type(2)));
typedef unsigned short  us4_t __attribute__((ext_vector_type(4)));
typedef unsigned short  us8_t __attribute__((ext_vector_type(8)));
typedef __bf16          bf8_t __attribute__((ext_vector_type(8)));

__device__ __forceinline__ float b2f(unsigned short u) {
    union { unsigned int u; float f; } v; v.u = ((unsigned int)u) << 16; return v.f;
}
__device__ __forceinline__ unsigned short f2b(float f) {
    union { float f; unsigned int u; } v; v.f = f;
    unsigned int u = v.u + 0x7fffu + ((v.u >> 16) & 1u);
    return (unsigned short)(u >> 16);
}
__device__ __forceinline__ unsigned cvt_pk_bf16(float lo, float hi) {
    unsigned r;
    asm("v_cvt_pk_bf16_f32 %0, %1, %2" : "=v"(r) : "v"(lo), "v"(hi));
    return r;
}
__device__ __forceinline__ void gll16(const unsigned short* g, unsigned short* l) {
    __builtin_amdgcn_global_load_lds((const __attribute__((address_space(1))) unsigned int*)g,
                                     (__attribute__((address_space(3))) unsigned int*)l,
                                     16, 0, 0);
}

// ---------------- fused prep: 6 weight transposes + bias concat + rope table + pre-LN ----------------
__global__ __launch_bounds__(256) void k_prep(const float* __restrict__ Wq, const float* __restrict__ Wk,
                                              const float* __restrict__ Wv, const float* __restrict__ Wo,
                                              const float* __restrict__ W1, const float* __restrict__ W2,
                                              const float* __restrict__ bq, const float* __restrict__ bk,
                                              const float* __restrict__ bv,
                                              const float* __restrict__ x,  const float* __restrict__ gpre,
                                              const float* __restrict__ bepre,
                                              unsigned short* __restrict__ WqkvT, unsigned short* __restrict__ WoT,
                                              unsigned short* __restrict__ W1T, unsigned short* __restrict__ W2T,
                                              float* __restrict__ bqkv, float* __restrict__ tab,
                                              unsigned short* __restrict__ xn) {
    const int j = blockIdx.x;
    if (j < 12288) {
        const float* src; unsigned short* dst; int R, C, jj;
        if (j < 3072)      { const int r = j >> 10; src = r == 0 ? Wq : (r == 1 ? Wk : Wv);
                             dst = WqkvT + (size_t)r * 1024 * 1024; R = 1024; C = 1024; jj = j & 1023; }
        else if (j < 4096) { src = Wo; dst = WoT; R = 1024; C = 1024; jj = j - 3072; }
        else if (j < 8192) { src = W1; dst = W1T; R = 1024; C = 4096; jj = j - 4096; }
        else               { src = W2; dst = W2T; R = 4096; C = 1024; jj = j - 8192; }
        const int ntx = C >> 5;
        const int bc = (jj % ntx) * 32, br = (jj / ntx) * 32;
        __shared__ float tile[32][33];
        const int tx = threadIdx.x & 31, ty = threadIdx.x >> 5;
#pragma unroll
        for (int i = ty; i < 32; i += 8)
            tile[i][tx] = src[(size_t)(br + i) * C + bc + tx];
        __syncthreads();
#pragma unroll
        for (int i = ty; i < 32; i += 8)
            dst[(size_t)(bc + i) * R + br + tx] = f2b(tile[tx][i]);
    } else if (j < 12300) {
        const int t = (j - 12288) * 256 + threadIdx.x;
        if (t < 1024) bqkv[t] = bq[t];
        else if (t < 2048) bqkv[t] = bk[t - 1024];
        else if (t < 3072) bqkv[t] = bv[t - 2048];
    } else if (j < 12308) {
        const int base = (j - 12300) * 256 + threadIdx.x;
#pragma unroll
        for (int e = 0; e < 32; e++) {
            const int idx = base + e * 2048;
            const int s = idx >> 5, i = idx & 31;
            const float freq = exp2f(-(float)i * 0.4152410118609203f);
            float sn, cs;
            sincosf((float)s * freq, &sn, &cs);
            tab[s * 64 + i] = cs;
            tab[s * 64 + 32 + i] = sn;
        }
    } else {
        // pre-attention layernorm, row = j - 12308
        const int row = j - 12308;
        const int t = threadIdx.x;
        const float* xr = x + (size_t)row * D_;
        f4_t v = *(const f4_t*)&xr[t * 4];
        float s = v[0] + v[1] + v[2] + v[3];
#pragma unroll
        for (int o = 32; o >= 1; o >>= 1) s += __shfl_down(s, o);
        __shared__ float red[4];
        const int w = t >> 6, lane = t & 63;
        if (lane == 0) red[w] = s;
        __syncthreads();
        const float mean = (red[0] + red[1] + red[2] + red[3]) * (1.f / D_);
        f4_t d;
#pragma unroll
        for (int c = 0; c < 4; c++) d[c] = v[c] - mean;
        float ss = d[0]*d[0] + d[1]*d[1] + d[2]*d[2] + d[3]*d[3];
#pragma unroll
        for (int o = 32; o >= 1; o >>= 1) ss += __shfl_down(ss, o);
        __syncthreads();
        if (lane == 0) red[w] = ss;
        __syncthreads();
        const float var = (red[0] + red[1] + red[2] + red[3]) * (1.f / D_);
        const float rstd = rsqrtf(var + 1e-5f);
        f4_t gv = *(const f4_t*)&gpre[t * 4];
        f4_t bv = *(const f4_t*)&bepre[t * 4];
        us4_t o4;
#pragma unroll
        for (int c = 0; c < 4; c++) o4[c] = f2b(d[c] * rstd * gv[c] + bv[c]);
        *(us4_t*)&xn[(size_t)row * D_ + t * 4] = o4;
    }
}

// ---------------- layernorm fp32 row(1024) -> bf16 ----------------
__global__ __launch_bounds__(256) void k_layernorm(const float* __restrict__ x,
                                                   const float* __restrict__ g,
                                                   const float* __restrict__ be,
                                                   unsigned short* __restrict__ out) {
    const int row = blockIdx.x;
    const int t = threadIdx.x;
    const float* xr = x + (size_t)row * D_;
    f4_t v = *(const f4_t*)&xr[t * 4];
    float s = v[0] + v[1] + v[2] + v[3];
#pragma unroll
    for (int o = 32; o >= 1; o >>= 1) s += __shfl_down(s, o);
    __shared__ float red[4];
    const int w = t >> 6, lane = t & 63;
    if (lane == 0) red[w] = s;
    __syncthreads();
    const float mean = (red[0] + red[1] + red[2] + red[3]) * (1.f / D_);
    f4_t d;
#pragma unroll
    for (int c = 0; c < 4; c++) d[c] = v[c] - mean;
    float ss = d[0]*d[0] + d[1]*d[1] + d[2]*d[2] + d[3]*d[3];
#pragma unroll
    for (int o = 32; o >= 1; o >>= 1) ss += __shfl_down(ss, o);
    __syncthreads();
    if (lane == 0) red[w] = ss;
    __syncthreads();
    const float var = (red[0] + red[1] + red[2] + red[3]) * (1.f / D_);
    const float rstd = rsqrtf(var + 1e-5f);
    f4_t gv = *(const f4_t*)&g[t * 4];
    f4_t bv = *(const f4_t*)&be[t * 4];
    us4_t o4;
#pragma unroll
    for (int c = 0; c < 4; c++) o4[c] = f2b(d[c] * rstd * gv[c] + bv[c]);
    *(us4_t*)&out[(size_t)row * D_ + t * 4] = o4;
}

#define VMW(n) asm volatile("s_waitcnt vmcnt(" #n ")" ::: "memory")
#define BAR()  __builtin_amdgcn_s_barrier()

// ---------------- bf16 MFMA GEMM 128x128, BK=32, counted-vmcnt dbuf, XCD-chunked 1D grid ----------------
// ROPE: bias+rotary on Q/K blocks; V blocks get bias + fused chunk column-sums to vsout.
// SPLIT: K-split partial (half = nid>>8), bf16 raw store.
template<int RELU, int BF16OUT, int RESID, int ROPE, int SPLIT>
__global__ __launch_bounds__(256) void k_gemm_bt(const unsigned short* __restrict__ A,
                                                 const unsigned short* __restrict__ Bt,
                                                 const float* __restrict__ bias,
                                                 const float* __restrict__ resid,
                                                 void* __restrict__ Cout,
                                                 const float* __restrict__ tab,
                                                 float* __restrict__ vsout,
                                                 int M, int N, int K, int ldk, int nbx) {
    __shared__ __align__(16) unsigned short As0[128 * 32];
    __shared__ __align__(16) unsigned short Bs0[128 * 32];
    __shared__ __align__(16) unsigned short As1[128 * 32];
    __shared__ __align__(16) unsigned short Bs1[128 * 32];
    const int tid = threadIdx.x;
    const int cpx = gridDim.x >> 3;
    int nid = (blockIdx.x & 7) * cpx + (blockIdx.x >> 3);
    int half = 0;
    if (SPLIT) { half = nid >> 8; nid &= 255; A += 2048 * half; Bt += 2048 * half; }
    const int m0 = (nid / nbx) * 128, n0 = (nid % nbx) * 128;
    const int w = tid >> 6, lane = tid & 63;
    const int wr = w >> 1, wc = w & 1;
    const int lr = lane & 15, lg = lane >> 4;

    f4_t acc[4][4] = {};

    const int r1 = tid >> 2, q1 = tid & 3;
    const unsigned short* pA1 = A + (size_t)(m0 + r1) * ldk + q1 * 8;
    const unsigned short* pA2 = pA1 + (size_t)64 * ldk;
    const unsigned short* pB1 = Bt + (size_t)(n0 + r1) * ldk + q1 * 8;
    const unsigned short* pB2 = pB1 + (size_t)64 * ldk;
    const int wofs = w * 512;

#define STAGE(AS, BS, kk) do {                 \
        gll16(pA1 + (kk), (AS) + wofs);        \
        gll16(pA2 + (kk), (AS) + 2048 + wofs); \
        gll16(pB1 + (kk), (BS) + wofs);        \
        gll16(pB2 + (kk), (BS) + 2048 + wofs); } while (0)

#define COMPUTE(AS, BS) do {                                                     \
        bf8_t af[4], bfr[4];                                                     \
        _Pragma("unroll")                                                        \
        for (int f = 0; f < 4; f++) {                                            \
            af[f]  = *(const bf8_t*)&(AS)[(wr * 64 + f * 16 + lr) * 32 + lg * 8];\
            bfr[f] = *(const bf8_t*)&(BS)[(wc * 64 + f * 16 + lr) * 32 + lg * 8];\
        }                                                                        \
        _Pragma("unroll")                                                        \
        for (int mf = 0; mf < 4; mf++)                                           \
            _Pragma("unroll")                                                    \
            for (int nf = 0; nf < 4; nf++)                                       \
                acc[mf][nf] = __builtin_amdgcn_mfma_f32_16x16x32_bf16(           \
                    af[mf], bfr[nf], acc[mf][nf], 0, 0, 0); } while (0)

    STAGE(As0, Bs0, 0);
    for (int k0 = 0; k0 + 64 < K; k0 += 64) {
        STAGE(As1, Bs1, k0 + 32);
        VMW(4); BAR();
        COMPUTE(As0, Bs0);
        BAR();
        STAGE(As0, Bs0, k0 + 64);
        VMW(4); BAR();
        COMPUTE(As1, Bs1);
        BAR();
    }
    STAGE(As1, Bs1, K - 32);
    VMW(4); BAR();
    COMPUTE(As0, Bs0);
    VMW(0); BAR();
    COMPUTE(As1, Bs1);
#undef STAGE
#undef COMPUTE

    if (SPLIT) {
        unsigned short* outp = (unsigned short*)Cout + (size_t)half * ((size_t)M * N);
#pragma unroll
        for (int mf = 0; mf < 4; mf++)
#pragma unroll
            for (int nf = 0; nf < 4; nf++) {
                const int n = n0 + wc * 64 + nf * 16 + lr;
#pragma unroll
                for (int j = 0; j < 4; j++) {
                    const int m = m0 + wr * 64 + mf * 16 + lg * 4 + j;
                    outp[(size_t)m * N + n] = f2b(acc[mf][nf][j]);
                }
            }
        return;
    }
    if (ROPE) {
        // bias first (reference ropes post-bias)
#pragma unroll
        for (int mf = 0; mf < 4; mf++)
#pragma unroll
            for (int nf = 0; nf < 4; nf++) {
                const float bv = bias[n0 + wc * 64 + nf * 16 + lr];
#pragma unroll
                for (int j = 0; j < 4; j++) acc[mf][nf][j] += bv;
            }
        if (n0 < 2048) {   // Q or K block: rotate (i, i+32) pairs = (nf, nf+2), i = nf*16+lr
#pragma unroll
            for (int mf = 0; mf < 4; mf++)
#pragma unroll
                for (int j = 0; j < 4; j++) {
                    const int srow = (m0 + wr * 64 + mf * 16 + lg * 4 + j) & 2047;
                    const float* tr = tab + srow * 64;
#pragma unroll
                    for (int t = 0; t < 2; t++) {
                        const float cs = tr[t * 16 + lr];
                        const float sn = tr[32 + t * 16 + lr];
                        const float lo = acc[mf][t][j], hi = acc[mf][t + 2][j];
                        acc[mf][t][j]     = lo * cs - hi * sn;
                        acc[mf][t + 2][j] = hi * cs + lo * sn;
                    }
                }
        } else {
            // V block: fused chunk column-sums (wave = one chunk x one head)
            float csum[4];
#pragma unroll
            for (int nf = 0; nf < 4; nf++) {
                float s = 0.f;
#pragma unroll
                for (int mf = 0; mf < 4; mf++)
#pragma unroll
                    for (int j = 0; j < 4; j++) s += acc[mf][nf][j];
                s += __shfl_xor(s, 16);
                s += __shfl_xor(s, 32);
                csum[nf] = s;
            }
            if (lg == 0) {
                const int mrow = m0 + wr * 64;
                const int bb = mrow >> 11, c = (mrow & 2047) >> 6;
                const int ncol0 = n0 + wc * 64;
                const int hh = (ncol0 - 2048) >> 6;
                const int bh = bb * 16 + hh;
#pragma unroll
                for (int nf = 0; nf < 4; nf++)
                    vsout[((size_t)(bh * 32 + c)) * 64 + nf * 16 + lr] = csum[nf];
            }
        }
        unsigned short* outp = (unsigned short*)Cout;
#pragma unroll
        for (int mf = 0; mf < 4; mf++)
#pragma unroll
            for (int nf = 0; nf < 4; nf++) {
                const int n = n0 + wc * 64 + nf * 16 + lr;
#pragma unroll
                for (int j = 0; j < 4; j++) {
                    const int m = m0 + wr * 64 + mf * 16 + lg * 4 + j;
                    outp[(size_t)m * N + n] = f2b(acc[mf][nf][j]);
                }
            }
        return;
    }
#pragma unroll
    for (int mf = 0; mf < 4; mf++) {
#pragma unroll
        for (int nf = 0; nf < 4; nf++) {
            const int n = n0 + wc * 64 + nf * 16 + lr;
            const float bv = bias[n];
#pragma unroll
            for (int j = 0; j < 4; j++) {
                const int m = m0 + wr * 64 + mf * 16 + lg * 4 + j;
                float val = acc[mf][nf][j] + bv;
                if (RESID) val += resid[(size_t)m * N + n];
                if (RELU) val = fmaxf(val, 0.f);
                if (BF16OUT) ((unsigned short*)Cout)[(size_t)m * N + n] = f2b(val);
                else         ((float*)Cout)[(size_t)m * N + n] = val;
            }
        }
    }
}

// ---------------- bf16 MFMA GEMM 64x128, BK=32, counted-vmcnt dbuf ----------------
template<int RELU, int BF16OUT, int RESID>
__global__ __launch_bounds__(256) void k_gemm64(const unsigned short* __restrict__ A,
                                                const unsigned short* __restrict__ Bt,
                                                const float* __restrict__ bias,
                                                const float* __restrict__ resid,
                                                void* __restrict__ Cout,
                                                int M, int N, int K, int ldk, int nbx) {
    __shared__ __align__(16) unsigned short As0[64 * 32];
    __shared__ __align__(16) unsigned short Bs0[128 * 32];
    __shared__ __align__(16) unsigned short As1[64 * 32];
    __shared__ __align__(16) unsigned short Bs1[128 * 32];
    const int tid = threadIdx.x;
    const int cpx = gridDim.x >> 3;
    const int nid = (blockIdx.x & 7) * cpx + (blockIdx.x >> 3);
    const int m0 = (nid / nbx) * 64, n0 = (nid % nbx) * 128;
    const int w = tid >> 6, lane = tid & 63;
    const int wr = w >> 1, wc = w & 1;
    const int lr = lane & 15, lg = lane >> 4;

    f4_t acc[2][4] = {};

    const int r1 = tid >> 2, q1 = tid & 3;
    const unsigned short* pA1 = A + (size_t)(m0 + r1) * ldk + q1 * 8;
    const unsigned short* pB1 = Bt + (size_t)(n0 + r1) * ldk + q1 * 8;
    const unsigned short* pB2 = pB1 + (size_t)64 * ldk;
    const int wofs = w * 512;

#define STAGE(AS, BS, kk) do {                 \
        gll16(pA1 + (kk), (AS) + wofs);        \
        gll16(pB1 + (kk), (BS) + wofs);        \
        gll16(pB2 + (kk), (BS) + 2048 + wofs); } while (0)

#define COMPUTE(AS, BS) do {                                                     \
        bf8_t af[2], bfr[4];                                                     \
        _Pragma("unroll")                                                        \
        for (int f = 0; f < 2; f++)                                              \
            af[f] = *(const bf8_t*)&(AS)[(wr * 32 + f * 16 + lr) * 32 + lg * 8]; \
        _Pragma("unroll")                                                        \
        for (int f = 0; f < 4; f++)                                              \
            bfr[f] = *(const bf8_t*)&(BS)[(wc * 64 + f * 16 + lr) * 32 + lg * 8];\
        _Pragma("unroll")                                                        \
        for (int mf = 0; mf < 2; mf++)                                           \
            _Pragma("unroll")                                                    \
            for (int nf = 0; nf < 4; nf++)                                       \
                acc[mf][nf] = __builtin_amdgcn_mfma_f32_16x16x32_bf16(           \
                    af[mf], bfr[nf], acc[mf][nf], 0, 0, 0); } while (0)

    STAGE(As0, Bs0, 0);
    for (int k0 = 0; k0 + 64 < K; k0 += 64) {
        STAGE(As1, Bs1, k0 + 32);
        VMW(3); BAR();
        COMPUTE(As0, Bs0);
        BAR();
        STAGE(As0, Bs0, k0 + 64);
        VMW(3); BAR();
        COMPUTE(As1, Bs1);
        BAR();
    }
    STAGE(As1, Bs1, K - 32);
    VMW(3); BAR();
    COMPUTE(As0, Bs0);
    VMW(0); BAR();
    COMPUTE(As1, Bs1);
#undef STAGE
#undef COMPUTE

#pragma unroll
    for (int mf = 0; mf < 2; mf++) {
#pragma unroll
        for (int nf = 0; nf < 4; nf++) {
            const int n = n0 + wc * 64 + nf * 16 + lr;
            const float bv = bias[n];
#pragma unroll
            for (int j = 0; j < 4; j++) {
                const int m = m0 + wr * 32 + mf * 16 + lg * 4 + j;
                float val = acc[mf][nf][j] + bv;
                if (RESID) val += resid[(size_t)m * N + n];
                if (RELU) val = fmaxf(val, 0.f);
                if (BF16OUT) ((unsigned short*)Cout)[(size_t)m * N + n] = f2b(val);
                else         ((float*)Cout)[(size_t)m * N + n] = val;
            }
        }
    }
}

// ---------------- FFN2 split-K combine: out = x2 + b2 + p0 + p1 ----------------
__global__ __launch_bounds__(256) void k_comb(const unsigned short* __restrict__ p,
                                              const float* __restrict__ x2,
                                              const float* __restrict__ b2,
                                              float* __restrict__ out) {
    const size_t idx = ((size_t)blockIdx.x * 256 + threadIdx.x) * 8;
    us8_t a = *(const us8_t*)(p + idx);
    us8_t b = *(const us8_t*)(p + (size_t)M_ * D_ + idx);
    const int n = (int)(idx & (D_ - 1));
    f4_t x0 = *(const f4_t*)(x2 + idx), x1 = *(const f4_t*)(x2 + idx + 4);
    f4_t b0 = *(const f4_t*)(b2 + n),  b1 = *(const f4_t*)(b2 + n + 4);
    f4_t o0, o1;
#pragma unroll
    for (int c = 0; c < 4; c++) {
        o0[c] = x0[c] + b0[c] + b2f(a[c]) + b2f(b[c]);
        o1[c] = x1[c] + b1[c] + b2f(a[4 + c]) + b2f(b[4 + c]);
    }
    *(f4_t*)(out + idx) = o0;
    *(f4_t*)(out + idx + 4) = o1;
}

// ---------------- exclusive scan of chunk sums -> pre[bh][33][64] ----------------
__global__ __launch_bounds__(64) void k_vscan(const float* __restrict__ sums,
                                              float* __restrict__ pre) {
    const int bh = blockIdx.x, d = threadIdx.x;
    float cum = 0.f;
    for (int c = 0; c < 32; c++) {
        pre[((size_t)bh * 33 + c) * 64 + d] = cum;
        cum += sums[((size_t)bh * 32 + c) * 64 + d];
    }
    pre[((size_t)bh * 33 + 32) * 64 + d] = cum;
}

// ---------------- MFMA flash attention: complementary q-tile pairs, uniform block work ----------------
// V staged as adjacent-row pairs -> packed b32 LDS writes (same layout, half the write issues).
#define KS_STRIDE 72   // K tile pad: 64+8

__global__ __launch_bounds__(256) void k_attn_mfma(const unsigned short* __restrict__ QKV,
                                                   const float* __restrict__ vpre,
                                                   unsigned short* __restrict__ Out) {
    __shared__ __align__(16) unsigned short Ks[2][64 * KS_STRIDE];     // [k][d] padded
    __shared__ __align__(16) unsigned short Vt[2][64 * 64];            // [d][kv] chunk-swizzled
    __shared__ __align__(16) unsigned short Ps[4][2][16 * KS_STRIDE];  // per-wave, per-subtile [q][k]

    const int id = blockIdx.x;                   // 512 blocks
    const int wg = (id & 7) * 64 + (id >> 3);    // XCD-chunked bijective swizzle (512%8==0)
    const int qA = wg & 15;                      // tile A chunk index (0..15)
    const int qB = 31 - qA;                      // tile B chunk index (16..31)
    const int bh = wg >> 4;
    const int b = bh >> 4, h = bh & 15;
    const int tid = threadIdx.x;
    const int wq = tid >> 6;
    const int lane = tid & 63;
    const int lr = lane & 15, lg = lane >> 4;

    const unsigned short* Qp = QKV;
    const unsigned short* Kp = QKV + 1024;
    const unsigned short* Vp = QKV + 2048;

    const int kcdt[2] = {qA, qB};
    const int lastV = qB;
    const int qb = wq * 16 + lr;
    const int q0t[2] = {qA * 64, qB * 64};

    // Q fragments per subtile (B-operand: q = lr), pre-scaled by (1/8)*log2(e)
    bf8_t qfrag[2][2];
#pragma unroll
    for (int t = 0; t < 2; t++) {
        const float qs = 0.125f * 1.44269504f;
        const size_t qbase = ((size_t)(b * S_ + q0t[t] + wq * 16 + lr)) * QKV_STR + h * HD_;
#pragma unroll
        for (int ks = 0; ks < 2; ks++) {
            us8_t raw = *(const us8_t*)(Qp + qbase + ks * 32 + lg * 8);
            ui4_t p;
#pragma unroll
            for (int e = 0; e < 4; e++)
                p[e] = cvt_pk_bf16(b2f(raw[e * 2]) * qs, b2f(raw[e * 2 + 1]) * qs);
            union { ui4_t u; bf8_t b; } c; c.u = p;
            qfrag[t][ks] = c.b;
        }
    }

    // staging geometry: K rows (row0, row0+32); V rows (2*rv, 2*rv+1) packed b32
    const int row0 = tid >> 3, g = tid & 7;
    const int row1 = row0 + 32;
    const int rv = tid >> 3;                     // 0..31 row-pair index
    const unsigned short* pK0 = Kp + ((size_t)(b * S_ + row0)) * QKV_STR + h * HD_ + g * 8;
    const unsigned short* pK1 = Kp + ((size_t)(b * S_ + row1)) * QKV_STR + h * HD_ + g * 8;
    const unsigned short* pV0 = Vp + ((size_t)(b * S_ + 2 * rv)) * QKV_STR + h * HD_ + g * 8;
    const unsigned short* pV1 = pV0 + QKV_STR;   // row 2*rv+1
    const int vw = (((rv >> 2) ^ g) << 3) + (rv & 3) * 2;   // slot + within-slot offset (even)

    float l_run[2] = {0.f, 0.f};
    f4_t acc_o[2][4] = {};
    f4_t acc_pre[2][4] = {};

    // prologue
    ui4_t ck0 = *(const ui4_t*)pK0;
    ui4_t ck1 = *(const ui4_t*)pK1;
    ui4_t cv0 = *(const ui4_t*)pV0;
    ui4_t cv1 = *(const ui4_t*)pV1;
    *(ui4_t*)&Ks[0][row0 * KS_STRIDE + g * 8] = ck0;
    *(ui4_t*)&Ks[0][row1 * KS_STRIDE + g * 8] = ck1;
    {
        const unsigned short* v0 = (const unsigned short*)&cv0;
        const unsigned short* v1 = (const unsigned short*)&cv1;
#pragma unroll
        for (int e = 0; e < 8; e++) {
            const int d = g * 8 + e;
            *(unsigned*)&Vt[0][d * 64 + vw] = (unsigned)v0[e] | ((unsigned)v1[e] << 16);
        }
    }
    {
        const size_t koff = (size_t)64 * QKV_STR;
        ck0 = *(const ui4_t*)(pK0 + koff);
        ck1 = *(const ui4_t*)(pK1 + koff);
        cv0 = *(const ui4_t*)(pV0 + koff);
        cv1 = *(const ui4_t*)(pV1 + koff);
    }
    __syncthreads();

#define VSLOT(dd, ks) ((((ks) * 4 + lg) ^ (((dd) * 2 + (lr >> 3)) & 7)) << 3)

    for (int kc = 0; kc < 32; kc++) {
        const int cur = kc & 1;
        const unsigned short* Kc = Ks[cur];
        const unsigned short* Vc = Vt[cur];

        // S^T = K·Q^T for both subtiles; K frag read once, used twice
        f4_t s4[2][4] = {};
        __builtin_amdgcn_s_setprio(1);
#pragma unroll
        for (int ks = 0; ks < 2; ks++) {
#pragma unroll
            for (int kk = 0; kk < 4; kk++) {
                bf8_t kfr = *(const bf8_t*)&Kc[(kk * 16 + lr) * KS_STRIDE + ks * 32 + lg * 8];
                s4[0][kk] = __builtin_amdgcn_mfma_f32_16x16x32_bf16(kfr, qfrag[0][ks], s4[0][kk], 0, 0, 0);
                s4[1][kk] = __builtin_amdgcn_mfma_f32_16x16x32_bf16(kfr, qfrag[1][ks], s4[1][kk], 0, 0, 0);
            }
        }
        __builtin_amdgcn_s_setprio(0);

        // stage next chunk (overlaps compute)
        if (kc < 31) {
            unsigned short* Kn = Ks[cur ^ 1];
            *(ui4_t*)&Kn[row0 * KS_STRIDE + g * 8] = ck0;
            *(ui4_t*)&Kn[row1 * KS_STRIDE + g * 8] = ck1;
            if (kc + 1 <= lastV) {
                unsigned short* Vn = Vt[cur ^ 1];
                const unsigned short* v0 = (const unsigned short*)&cv0;
                const unsigned short* v1 = (const unsigned short*)&cv1;
#pragma unroll
                for (int e = 0; e < 8; e++) {
                    const int d = g * 8 + e;
                    *(unsigned*)&Vn[d * 64 + vw] = (unsigned)v0[e] | ((unsigned)v1[e] << 16);
                }
            }
        }
        if (kc < 30) {
            const size_t koff = (size_t)(kc + 2) * 64 * QKV_STR;
            ck0 = *(const ui4_t*)(pK0 + koff);
            ck1 = *(const ui4_t*)(pK1 + koff);
            if (kc + 2 <= lastV) {
                cv0 = *(const ui4_t*)(pV0 + koff);
                cv1 = *(const ui4_t*)(pV1 + koff);
            }
        }

        // fixed-max softmax: p = exp2(s), l += sum(p)
#pragma unroll
        for (int t = 0; t < 2; t++) {
            float cs = 0.f;
#pragma unroll
            for (int kk = 0; kk < 4; kk++)
#pragma unroll
                for (int j = 0; j < 4; j++) {
                    const float p = __builtin_amdgcn_exp2f(s4[t][kk][j]);
                    s4[t][kk][j] = p;
                    cs += p;
                }
            cs += __shfl_xor(cs, 16);
            cs += __shfl_xor(cs, 32);
            l_run[t] += cs;
        }

        if (kc <= qB) {
            const bool doA = (kc <= qA);
#pragma unroll
            for (int kk = 0; kk < 4; kk++) {
                const int kb = kk * 16 + lg * 4;
                ui2_t wd;
                if (kc == qB) {
                    wd[0] = cvt_pk_bf16(kb + 0 <= qb ? s4[1][kk][0] : 0.f,
                                        kb + 1 <= qb ? s4[1][kk][1] : 0.f);
                    wd[1] = cvt_pk_bf16(kb + 2 <= qb ? s4[1][kk][2] : 0.f,
                                        kb + 3 <= qb ? s4[1][kk][3] : 0.f);
                } else {
                    wd[0] = cvt_pk_bf16(s4[1][kk][0], s4[1][kk][1]);
                    wd[1] = cvt_pk_bf16(s4[1][kk][2], s4[1][kk][3]);
                }
                *(ui2_t*)&Ps[wq][1][lr * KS_STRIDE + kk * 16 + lg * 4] = wd;
            }
            if (doA) {
#pragma unroll
                for (int kk = 0; kk < 4; kk++) {
                    const int kb = kk * 16 + lg * 4;
                    ui2_t wd;
                    if (kc == qA) {
                        wd[0] = cvt_pk_bf16(kb + 0 <= qb ? s4[0][kk][0] : 0.f,
                                            kb + 1 <= qb ? s4[0][kk][1] : 0.f);
                        wd[1] = cvt_pk_bf16(kb + 2 <= qb ? s4[0][kk][2] : 0.f,
                                            kb + 3 <= qb ? s4[0][kk][3] : 0.f);
                    } else {
                        wd[0] = cvt_pk_bf16(s4[0][kk][0], s4[0][kk][1]);
                        wd[1] = cvt_pk_bf16(s4[0][kk][2], s4[0][kk][3]);
                    }
                    *(ui2_t*)&Ps[wq][0][lr * KS_STRIDE + kk * 16 + lg * 4] = wd;
                }
            }
            __builtin_amdgcn_s_setprio(1);
#pragma unroll
            for (int ks = 0; ks < 2; ks++) {
                bf8_t pf1 = *(const bf8_t*)&Ps[wq][1][lr * KS_STRIDE + ks * 32 + lg * 8];
                bf8_t pf0;
                if (doA) pf0 = *(const bf8_t*)&Ps[wq][0][lr * KS_STRIDE + ks * 32 + lg * 8];
#pragma unroll
                for (int dd = 0; dd < 4; dd++) {
                    bf8_t vf = *(const bf8_t*)&Vc[(dd * 16 + lr) * 64 + VSLOT(dd, ks)];
                    acc_o[1][dd] = __builtin_amdgcn_mfma_f32_16x16x32_bf16(vf, pf1, acc_o[1][dd], 0, 0, 0);
                    if (doA)
                        acc_o[0][dd] = __builtin_amdgcn_mfma_f32_16x16x32_bf16(vf, pf0, acc_o[0][dd], 0, 0, 0);
                }
            }
            __builtin_amdgcn_s_setprio(0);

            // diagonal partial prefix (subtile-specific kc)
#pragma unroll
            for (int t = 0; t < 2; t++) {
                if (kc == kcdt[t]) {
                    unsigned short* Pw = Ps[wq][t];
#pragma unroll
                    for (int kk = 0; kk < 4; kk++) {
                        const int kb = kk * 16 + lg * 4;
                        ui2_t wd;
                        wd[0] = (kb + 0 <= qb ? 0x3f80u : 0u) | ((kb + 1 <= qb ? 0x3f80u : 0u) << 16);
                        wd[1] = (kb + 2 <= qb ? 0x3f80u : 0u) | ((kb + 3 <= qb ? 0x3f80u : 0u) << 16);
                        *(ui2_t*)&Pw[lr * KS_STRIDE + kk * 16 + lg * 4] = wd;
                    }
#pragma unroll
                    for (int ks = 0; ks < 2; ks++) {
                        bf8_t pf = *(const bf8_t*)&Pw[lr * KS_STRIDE + ks * 32 + lg * 8];
#pragma unroll
                        for (int dd = 0; dd < 4; dd++) {
                            bf8_t vf = *(const bf8_t*)&Vc[(dd * 16 + lr) * 64 + VSLOT(dd, ks)];
                            acc_pre[t][dd] = __builtin_amdgcn_mfma_f32_16x16x32_bf16(vf, pf, acc_pre[t][dd], 0, 0, 0);
                        }
                    }
                }
            }
        }
        __syncthreads();
    }
#undef VSLOT

    // out = O/l - 1e9 * (total - chunkprefix[kcd_t] - diag_prefix)
    const float* Ct = vpre + ((size_t)bh * 33 + 32) * 64;
#pragma unroll
    for (int t = 0; t < 2; t++) {
        const float* Cq = vpre + ((size_t)bh * 33 + kcdt[t]) * 64;
        const float inv_l = 1.f / l_run[t];
        const size_t obase = ((size_t)(b * S_ + q0t[t] + wq * 16 + lr)) * D_ + h * HD_;
#pragma unroll
        for (int dd = 0; dd < 4; dd++) {
            const f4_t tq4 = *(const f4_t*)&Cq[dd * 16 + lg * 4];
            const f4_t tt4 = *(const f4_t*)&Ct[dd * 16 + lg * 4];
            float v[4];
#pragma unroll
            for (int j = 0; j < 4; j++)
                v[j] = acc_o[t][dd][j] * inv_l - 1e9f * (tt4[j] - tq4[j] - acc_pre[t][dd][j]);
            ui2_t wd;
            wd[0] = cvt_pk_bf16(v[0], v[1]);
            wd[1] = cvt_pk_bf16(v[2], v[3]);
            *(ui2_t*)&Out[obase + dd * 16 + lg * 4] = wd;
        }
    }
}

// ---------------- launch ----------------
extern "C" void kernel_launch(void* const* d_in, const int* in_sizes, int n_in,
                              void* d_out, int out_size, void* d_ws, size_t ws_size,
                              hipStream_t stream) {
    const float* x     = (const float*)d_in[0];
    const float* Wq    = (const float*)d_in[1];  const float* bq = (const float*)d_in[2];
    const float* Wk    = (const float*)d_in[3];  const float* bk = (const float*)d_in[4];
    const float* Wv    = (const float*)d_in[5];  const float* bv = (const float*)d_in[6];
    const float* Wo    = (const float*)d_in[7];  const float* bo = (const float*)d_in[8];
    const float* W1    = (const float*)d_in[9];  const float* b1 = (const float*)d_in[10];
    const float* W2    = (const float*)d_in[11]; const float* b2 = (const float*)d_in[12];
    const float* gpre  = (const float*)d_in[13]; const float* bepre  = (const float*)d_in[14];
    const float* gpost = (const float*)d_in[15]; const float* bepost = (const float*)d_in[16];

    char* ws = (char*)d_ws;
    const size_t MB = 1024 * 1024;
    unsigned short* psplit = (unsigned short*)(ws + 0 * MB);   // 16MB, FFN2 partials (over dead weights)
    unsigned short* WqkvT = (unsigned short*)(ws + 0 * MB);    // 6MB   (dead after QKV gemm)
    unsigned short* WoT   = (unsigned short*)(ws + 6 * MB);    // 2MB   (dead after O-proj)
    unsigned short* W1T   = (unsigned short*)(ws + 8 * MB);    // 8MB   (dead after FFN1)
    unsigned short* W2T   = (unsigned short*)(ws + 16 * MB);   // 8MB   (live until FFN2)
    unsigned short* xn    = (unsigned short*)(ws + 24 * MB);   // 8MB   (dead after QKV gemm)
    unsigned short* x2n   = (unsigned short*)(ws + 24 * MB);   // 8MB   (over xn)
    unsigned short* QKV   = (unsigned short*)(ws + 32 * MB);   // 24MB  (dead after attn)
    unsigned short* h1    = (unsigned short*)(ws + 32 * MB);   // 32MB  (over QKV+att)
    unsigned short* att   = (unsigned short*)(ws + 56 * MB);   // 8MB   (dead after O-proj)
    float*          x2    = (float*)(ws + 64 * MB);            // 16MB  (live to end)
    float*          bqkv  = (float*)(ws + 80 * MB);            // 12KB
    float*          vpre  = (float*)(ws + 80 * MB + 16384);    // 270KB
    float*          tab   = (float*)(ws + 80 * MB + 512 * 1024);  // 512KB rope table
    float*          vsum  = (float*)(ws + 81 * MB);            // 256KB

    // prep: transposes + bias + rope table + pre-LN (grid 12308 + 4096)
    k_prep<<<16404, 256, 0, stream>>>(Wq, Wk, Wv, Wo, W1, W2, bq, bk, bv,
                                      x, gpre, bepre,
                                      WqkvT, WoT, W1T, W2T, bqkv, tab, xn);

    // fused QKV projection + bias + RoPE + V chunk colsums (grid 768, nbx=24)
    k_gemm_bt<0, 1, 0, 1, 0><<<768, 256, 0, stream>>>(xn, WqkvT, bqkv, nullptr, QKV, tab, vsum,
                                                      M_, QKV_STR, D_, D_, 24);

    k_vscan<<<32, 64, 0, stream>>>(vsum, vpre);

    k_attn_mfma<<<512, 256, 0, stream>>>(QKV, vpre, att);

    k_gemm64<0, 0, 1><<<512, 256, 0, stream>>>(att, WoT, bo, x, x2, M_, D_, D_, D_, 8);

    k_layernorm<<<M_, 256, 0, stream>>>(x2, gpost, bepost, x2n);

    k_gemm_bt<1, 1, 0, 0, 0><<<1024, 256, 0, stream>>>(x2n, W1T, b1, nullptr, h1, nullptr, nullptr,
                                                       M_, DFF_, D_, D_, 32);

    // FFN2 split-K=2: grid 512, halves write bf16 partials
    k_gemm_bt<0, 1, 0, 0, 1><<<512, 256, 0, stream>>>(h1, W2T, nullptr, nullptr, psplit, nullptr, nullptr,
                                                      M_, D_, 2048, DFF_, 8);
    k_comb<<<2048, 256, 0, stream>>>(psplit, x2, b2, (float*)d_out);
}